// Round 3
// baseline (2379.650 us; speedup 1.0000x reference)
//
#include <hip/hip_runtime.h>
#include <hip/hip_bf16.h>

#define NQ 8
#define NC 1024
#define DD 128
#define BB 16
#define SS 2048
#define RR (BB * SS)   // 32768 rows
#define GAMMA_F 0.99f

// ---------------------------------------------------------------- helpers
typedef __attribute__((address_space(3))) void lds_void;
typedef const __attribute__((address_space(1))) void g1_void;

__device__ __forceinline__ void gload16(const void* g, void* l) {
  __builtin_amdgcn_global_load_lds((g1_void*)g, (lds_void*)l, 16, 0, 0);
}

__device__ __forceinline__ float dpp_xor1(float v) {
  int i = __builtin_amdgcn_mov_dpp(__float_as_int(v), 0xB1, 0xF, 0xF, true);
  return __int_as_float(i);
}
__device__ __forceinline__ float dpp_xor2(float v) {
  int i = __builtin_amdgcn_mov_dpp(__float_as_int(v), 0x4E, 0xF, 0xF, true);
  return __int_as_float(i);
}

// ---------------------------------------------------------------- transpose in
// res[b*SS+s][d] = data[b][d][s]
__global__ __launch_bounds__(256) void k_transpose_in(
    const float* __restrict__ data, float* __restrict__ res)
{
  __shared__ float tile[32][33];
  int b = blockIdx.z;
  int s0 = blockIdx.x << 5, d0 = blockIdx.y << 5;
  int tx = threadIdx.x, ty = threadIdx.y;   // (32,8)
  #pragma unroll
  for (int r = 0; r < 32; r += 8)
    tile[ty + r][tx] = data[((size_t)b * DD + d0 + ty + r) * SS + s0 + tx];
  __syncthreads();
  #pragma unroll
  for (int r = 0; r < 32; r += 8)
    res[((size_t)b * SS + s0 + ty + r) * DD + d0 + tx] = tile[tx][ty + r];
}

// ---------------------------------------------------------------- ||W||^2
__global__ void k_wsq(const float* __restrict__ W, float* __restrict__ wsq)
{
  int c = blockIdx.x * blockDim.x + threadIdx.x;
  if (c >= NQ * NC) return;
  const float4* p = reinterpret_cast<const float4*>(W + (size_t)c * DD);
  float s = 0.f;
  #pragma unroll 8
  for (int k = 0; k < DD / 4; ++k) {
    float4 v = p[k];
    s += v.x * v.x + v.y * v.y + v.z * v.z + v.w * v.w;
  }
  wsq[c] = s;
}

// ---------------------------------------------------------------- argmin GEMM
// 128 rows/block, 8 col-tiles of 128. 512 threads:
//   ks = t&3 (k-slice of 32 dims), tc = (t>>2)&7 (col group), tr = t>>5 (row group)
// micro-tile per thread: 8 rows x 16 cols (cols = tc + 8*j).
// LDS swizzles: R granule(row,c) at c ^ ((row>>3)&15); W granule at c ^ (row&15).
#define BR 128
#define BC 128
__global__ __launch_bounds__(512, 2) void k_argmin(
    const float* __restrict__ res, const float* __restrict__ W,
    const float* __restrict__ wsq, int* __restrict__ idx_out,
    float* __restrict__ idxf_out, int stage)
{
  __shared__ float4 R4[BR * 32];   // 64 KiB
  __shared__ float4 W4[BC * 32];   // 64 KiB
  const int t = threadIdx.x;
  const int ks = t & 3;
  const int tc = (t >> 2) & 7;
  const int tr = t >> 5;
  const int row0 = blockIdx.x * BR;
  const float* Ws = W + (size_t)stage * NC * DD;
  const float* wsqs = wsq + stage * NC;

  // stage R tile: LDS linear, global source pre-swizzled (involution)
  const float4* gres = reinterpret_cast<const float4*>(res + (size_t)row0 * DD);
  #pragma unroll
  for (int it = 0; it < 8; ++it) {
    int fi = it * 512 + t;
    int row = fi >> 5, c4 = fi & 31;
    gload16(&gres[row * 32 + (c4 ^ ((row >> 3) & 15))], &R4[fi]);
  }

  float best[8];
  int bidx[8];
  #pragma unroll
  for (int i = 0; i < 8; ++i) { best[i] = 3.4e38f; bidx[i] = 0; }

  const int trbase = tr * 256;       // granule base of this thread's rows

  for (int ct = 0; ct < NC / BC; ++ct) {
    __syncthreads();   // prior tile's LDS reads complete
    const float4* gw = reinterpret_cast<const float4*>(Ws + (size_t)ct * BC * DD);
    #pragma unroll
    for (int it = 0; it < 8; ++it) {
      int fi = it * 512 + t;
      int row = fi >> 5, c4 = fi & 31;
      gload16(&gw[row * 32 + (c4 ^ (row & 15))], &W4[fi]);
    }
    __syncthreads();   // drains vmcnt then barrier

    float acc[8][16];
    #pragma unroll
    for (int i = 0; i < 8; ++i)
      #pragma unroll
      for (int j = 0; j < 16; ++j) acc[i][j] = 0.f;

    #pragma unroll 2
    for (int kk = 0; kk < 8; ++kk) {
      int k4 = (ks << 3) + kk;
      const float4* pa = &R4[trbase + (k4 ^ tr)];
      float4 a[8];
      #pragma unroll
      for (int i = 0; i < 8; ++i) a[i] = pa[i * 32];
      int wx = k4 ^ tc;
      const float4* pbE = &W4[tc * 32 + wx];               // rows tc + 16*(j>>1)
      const float4* pbO = &W4[(tc + 8) * 32 + (wx ^ 8)];   // rows tc+8 + 16*(j>>1)
      #pragma unroll
      for (int j = 0; j < 16; ++j) {
        float4 bv = ((j & 1) ? pbO : pbE)[(j >> 1) * 512];
        #pragma unroll
        for (int i = 0; i < 8; ++i) {
          acc[i][j] = fmaf(a[i].x, bv.x, acc[i][j]);
          acc[i][j] = fmaf(a[i].y, bv.y, acc[i][j]);
          acc[i][j] = fmaf(a[i].z, bv.z, acc[i][j]);
          acc[i][j] = fmaf(a[i].w, bv.w, acc[i][j]);
        }
      }
    }

    // reduce partial dots across the 4 k-slice lanes (DPP butterfly, VALU-only)
    #pragma unroll
    for (int j = 0; j < 16; ++j) {
      int code = ct * BC + tc + 8 * j;
      float sq = wsqs[code];
      #pragma unroll
      for (int i = 0; i < 8; ++i) {
        float v = acc[i][j];
        v += dpp_xor1(v);
        v += dpp_xor2(v);
        float sc = fmaf(-2.f, v, sq);   // ||W||^2 - 2 r.W
        if (sc < best[i] || (sc == best[i] && code < bidx[i])) {
          best[i] = sc; bidx[i] = code;
        }
      }
    }
  }

  // reduce across the 8 tc groups (lane bits 2..4); ks lanes already agree
  #pragma unroll
  for (int m = 4; m <= 16; m <<= 1) {
    #pragma unroll
    for (int i = 0; i < 8; ++i) {
      float ov = __shfl_xor(best[i], m);
      int oi = __shfl_xor(bidx[i], m);
      if (ov < best[i] || (ov == best[i] && oi < bidx[i])) { best[i] = ov; bidx[i] = oi; }
    }
  }
  if ((t & 31) == 0) {
    #pragma unroll
    for (int i = 0; i < 8; ++i) {
      int row = row0 + tr * 8 + i;
      idx_out[row] = bidx[i];
      idxf_out[row] = (float)bidx[i];
    }
  }
}

// ---------------------------------------------------------------- per-row update
// 8 rows/block, float4 per thread
__global__ __launch_bounds__(256) void k_update(
    const float* __restrict__ res_cur, float* __restrict__ res_next,
    const float* __restrict__ W, const int* __restrict__ idx,
    float* __restrict__ counts, float* __restrict__ sums, int stage)
{
  int row = blockIdx.x * 8 + (threadIdx.x >> 5);
  int d4 = threadIdx.x & 31;
  int id = idx[row];
  const float4* rc = reinterpret_cast<const float4*>(res_cur + (size_t)row * DD);
  float4 r = rc[d4];
  const float4* wp = reinterpret_cast<const float4*>(W + ((size_t)stage * NC + id) * DD);
  float4 q = wp[d4];
  float4 o; o.x = r.x - q.x; o.y = r.y - q.y; o.z = r.z - q.z; o.w = r.w - q.w;
  reinterpret_cast<float4*>(res_next + (size_t)row * DD)[d4] = o;
  float* sb = &sums[(size_t)id * DD + d4 * 4];
  atomicAdd(sb + 0, r.x);
  atomicAdd(sb + 1, r.y);
  atomicAdd(sb + 2, r.z);
  atomicAdd(sb + 3, r.w);
  if (d4 == 0) atomicAdd(&counts[id], 1.0f);
}

// ---------------------------------------------------------------- threefry2x32 (JAX-exact)
__device__ __forceinline__ unsigned rotl32(unsigned v, int r) { return (v << r) | (v >> (32 - r)); }

__device__ void threefry2x32(unsigned ks0, unsigned ks1, unsigned x0, unsigned x1,
                             unsigned& o0, unsigned& o1)
{
  unsigned ks2 = ks0 ^ ks1 ^ 0x1BD11BDAu;
  x0 += ks0; x1 += ks1;
  x0 += x1; x1 = rotl32(x1, 13); x1 ^= x0;
  x0 += x1; x1 = rotl32(x1, 15); x1 ^= x0;
  x0 += x1; x1 = rotl32(x1, 26); x1 ^= x0;
  x0 += x1; x1 = rotl32(x1, 6);  x1 ^= x0;
  x0 += ks1; x1 += ks2 + 1u;
  x0 += x1; x1 = rotl32(x1, 17); x1 ^= x0;
  x0 += x1; x1 = rotl32(x1, 29); x1 ^= x0;
  x0 += x1; x1 = rotl32(x1, 16); x1 ^= x0;
  x0 += x1; x1 = rotl32(x1, 24); x1 ^= x0;
  x0 += ks2; x1 += ks0 + 2u;
  x0 += x1; x1 = rotl32(x1, 13); x1 ^= x0;
  x0 += x1; x1 = rotl32(x1, 15); x1 ^= x0;
  x0 += x1; x1 = rotl32(x1, 26); x1 ^= x0;
  x0 += x1; x1 = rotl32(x1, 6);  x1 ^= x0;
  x0 += ks0; x1 += ks1 + 3u;
  x0 += x1; x1 = rotl32(x1, 17); x1 ^= x0;
  x0 += x1; x1 = rotl32(x1, 29); x1 ^= x0;
  x0 += x1; x1 = rotl32(x1, 16); x1 ^= x0;
  x0 += x1; x1 = rotl32(x1, 24); x1 ^= x0;
  x0 += ks1; x1 += ks2 + 4u;
  x0 += x1; x1 = rotl32(x1, 13); x1 ^= x0;
  x0 += x1; x1 = rotl32(x1, 15); x1 ^= x0;
  x0 += x1; x1 = rotl32(x1, 26); x1 ^= x0;
  x0 += x1; x1 = rotl32(x1, 6);  x1 ^= x0;
  x0 += ks2; x1 += ks0 + 5u;
  o0 = x0; o1 = x1;
}

// ---------------------------------------------------------------- EMA / dead codes
__global__ __launch_bounds__(128) void k_finalize(
    const float* __restrict__ Ni_in, const float* __restrict__ mi_in,
    const float* __restrict__ counts, const float* __restrict__ sums,
    const float* __restrict__ res_cur,
    float* __restrict__ outNi, float* __restrict__ outmi, float* __restrict__ outW,
    int stage)
{
  const float ONEMG = (float)(1.0 - 0.99);
  int c = blockIdx.x, d = threadIdx.x;
  float cnt = counts[c];
  float ni = Ni_in[stage * NC + c] * GAMMA_F + cnt * ONEMG;
  float m = mi_in[((size_t)stage * NC + c) * DD + d] * GAMMA_F
          + sums[(size_t)c * DD + d] * ONEMG;
  float w = m / fmaxf(ni, 1e-8f);
  if (ni < 2.0f) {
    unsigned K0, K1, a0, a1, b0, b1, o0, o1;
    threefry2x32(0u, 42u, 0u, (unsigned)stage, K0, K1);   // fold_in
    threefry2x32(K0, K1, 0u, 2u, a0, a1);                 // split row 0
    threefry2x32(K0, K1, 1u, 3u, b0, b1);                 // split row 1
    unsigned bits;
    if (c < 512) { threefry2x32(a1, b1, (unsigned)c, (unsigned)(c + 512), o0, o1); bits = o0; }
    else         { threefry2x32(a1, b1, (unsigned)(c - 512), (unsigned)c, o0, o1); bits = o1; }
    int rid = (int)(bits & 32767u);
    w = res_cur[(size_t)rid * DD + d];
  }
  if (d == 0) outNi[stage * NC + c] = ni;
  size_t o = ((size_t)stage * NC + c) * DD + d;
  outmi[o] = m;
  outW[o] = w;
}

// ---------------------------------------------------------------- logits + loss partials
__global__ __launch_bounds__(256) void k_final(
    const float* __restrict__ data, const float* __restrict__ res,
    float* __restrict__ logits, float* __restrict__ partials)
{
  __shared__ float tile[32][33];
  __shared__ float wsum[4];
  int b = blockIdx.z, s0 = blockIdx.x << 5, d0 = blockIdx.y << 5;
  int tx = threadIdx.x, ty = threadIdx.y;
  #pragma unroll
  for (int r = 0; r < 32; r += 8)
    tile[ty + r][tx] = res[((size_t)b * SS + s0 + ty + r) * DD + d0 + tx];
  __syncthreads();
  float l = 0.f;
  #pragma unroll
  for (int r = 0; r < 32; r += 8) {
    int dv = d0 + ty + r, s = s0 + tx;
    size_t o = ((size_t)b * DD + dv) * SS + s;
    float rv = tile[tx][ty + r];
    logits[o] = data[o] - rv;         // == cur_y_t up to rounding
    l = fmaf(rv, rv, l);
  }
  #pragma unroll
  for (int m = 1; m < 64; m <<= 1) l += __shfl_xor(l, m);
  int lin = ty * 32 + tx;
  if ((lin & 63) == 0) wsum[lin >> 6] = l;
  __syncthreads();
  if (lin == 0) {
    int bl = (blockIdx.z * gridDim.y + blockIdx.y) * gridDim.x + blockIdx.x;
    partials[bl] = wsum[0] + wsum[1] + wsum[2] + wsum[3];
  }
}

__global__ __launch_bounds__(1024) void k_loss_reduce(
    const float* __restrict__ partials, float* __restrict__ loss)
{
  __shared__ float ws[16];
  int t = threadIdx.x;
  float s = partials[t] + partials[t + 1024] + partials[t + 2048] + partials[t + 3072];
  #pragma unroll
  for (int m = 1; m < 64; m <<= 1) s += __shfl_xor(s, m);
  if ((t & 63) == 0) ws[t >> 6] = s;
  __syncthreads();
  if (t < 16) {
    float v = ws[t];
    #pragma unroll
    for (int m = 1; m < 16; m <<= 1) v += __shfl_xor(v, m);
    if (t == 0) loss[0] = v * (1.0f / 4194304.0f);
  }
}

// ---------------------------------------------------------------- launch
extern "C" void kernel_launch(void* const* d_in, const int* in_sizes, int n_in,
                              void* d_out, int out_size, void* d_ws, size_t ws_size,
                              hipStream_t stream)
{
  (void)in_sizes; (void)n_in; (void)out_size; (void)ws_size;
  const float* data = (const float*)d_in[0];
  const float* W    = (const float*)d_in[1];
  const float* Ni   = (const float*)d_in[2];
  const float* mi   = (const float*)d_in[3];

  float* out        = (float*)d_out;
  float* out_logits = out;
  float* out_loss   = out + (size_t)BB * DD * SS;       // 4194304
  float* out_idx    = out_loss + 1;
  float* out_Ni     = out_idx + (size_t)NQ * RR;        // +262144
  float* out_mi     = out_Ni + (size_t)NQ * NC;         // +8192
  float* out_W      = out_mi + (size_t)NQ * NC * DD;    // +1048576

  float* resA     = (float*)d_ws;
  float* resB     = resA + (size_t)RR * DD;
  int*   idxw     = (int*)(resB + (size_t)RR * DD);
  float* counts   = (float*)(idxw + RR);
  float* sums     = counts + NC;
  float* wsq      = sums + (size_t)NC * DD;
  float* partials = wsq + NQ * NC;

  k_transpose_in<<<dim3(SS / 32, DD / 32, BB), dim3(32, 8), 0, stream>>>(data, resA);
  k_wsq<<<(NQ * NC + 255) / 256, 256, 0, stream>>>(W, wsq);

  float* cur = resA;
  float* nxt = resB;
  for (int i = 0; i < NQ; ++i) {
    hipMemsetAsync(counts, 0, (NC + (size_t)NC * DD) * sizeof(float), stream);
    k_argmin<<<RR / BR, 512, 0, stream>>>(cur, W, wsq, idxw, out_idx + (size_t)i * RR, i);
    k_update<<<RR / 8, 256, 0, stream>>>(cur, nxt, W, idxw, counts, sums, i);
    k_finalize<<<NC, 128, 0, stream>>>(Ni, mi, counts, sums, cur, out_Ni, out_mi, out_W, i);
    float* tmp = cur; cur = nxt; nxt = tmp;
  }

  k_final<<<dim3(SS / 32, DD / 32, BB), dim3(32, 8), 0, stream>>>(data, cur, out_logits, partials);
  k_loss_reduce<<<1, 1024, 0, stream>>>(partials, out_loss);
}

// Round 4
// 2296.274 us; speedup vs baseline: 1.0363x; 1.0363x over previous
//
#include <hip/hip_runtime.h>
#include <hip/hip_bf16.h>

#define NQ 8
#define NC 1024
#define DD 128
#define BB 16
#define SS 2048
#define RR (BB * SS)   // 32768 rows
#define GAMMA_F 0.99f

// ---------------------------------------------------------------- helpers
typedef __attribute__((address_space(3))) void lds_void;
typedef const __attribute__((address_space(1))) void g1_void;

__device__ __forceinline__ void gload16(const void* g, void* l) {
  __builtin_amdgcn_global_load_lds((g1_void*)g, (lds_void*)l, 16, 0, 0);
}

// ---------------------------------------------------------------- transpose in
// res[b*SS+s][d] = data[b][d][s]
__global__ __launch_bounds__(256) void k_transpose_in(
    const float* __restrict__ data, float* __restrict__ res)
{
  __shared__ float tile[32][33];
  int b = blockIdx.z;
  int s0 = blockIdx.x << 5, d0 = blockIdx.y << 5;
  int tx = threadIdx.x, ty = threadIdx.y;   // (32,8)
  #pragma unroll
  for (int r = 0; r < 32; r += 8)
    tile[ty + r][tx] = data[((size_t)b * DD + d0 + ty + r) * SS + s0 + tx];
  __syncthreads();
  #pragma unroll
  for (int r = 0; r < 32; r += 8)
    res[((size_t)b * SS + s0 + ty + r) * DD + d0 + tx] = tile[tx][ty + r];
}

// ---------------------------------------------------------------- ||W||^2
__global__ void k_wsq(const float* __restrict__ W, float* __restrict__ wsq)
{
  int c = blockIdx.x * blockDim.x + threadIdx.x;
  if (c >= NQ * NC) return;
  const float4* p = reinterpret_cast<const float4*>(W + (size_t)c * DD);
  float s = 0.f;
  #pragma unroll 8
  for (int k = 0; k < DD / 4; ++k) {
    float4 v = p[k];
    s += v.x * v.x + v.y * v.y + v.z * v.z + v.w * v.w;
  }
  wsq[c] = s;
}

// ---------------------------------------------------------------- argmin GEMM
// Block: 256 thr = 4 waves. Wave w owns rows row0 + w*16 .. +15 (wave-uniform).
// Each lane owns 4 cols per 256-col tile: col = tile0 + j*64 + lane.
// Block covers 64 rows x 512 cols (half = blockIdx.y); 2 col-tiles x 4 k-chunks.
// LDS: A-chunk 64 rows x 32 dims (granule (r,g) at r*8+g), 8 KiB;
//      B-chunk 256 cols x 32 dims TRANSPOSED (granule (g,c) at g*256+c), 32 KiB.
// A-reads are wave-uniform broadcasts; B-reads have consecutive lanes on
// consecutive granules (bank-quads cycle 0..7 -> conflict-free).
__global__ __launch_bounds__(256, 4) void k_argmin(
    const float* __restrict__ res, const float* __restrict__ W,
    const float* __restrict__ wsq,
    float* __restrict__ pbest, int* __restrict__ pidx, int stage)
{
  __shared__ float4 A4[64 * 8];     // 8 KiB
  __shared__ float4 B4[8 * 256];    // 32 KiB
  const int t = threadIdx.x;
  const int lane = t & 63;
  const int rg = t >> 6;            // wave id 0..3
  const int row0 = blockIdx.x * 64;
  const int half = blockIdx.y;      // 0: cols 0-511, 1: cols 512-1023
  const float* Ws = W + (size_t)stage * NC * DD;
  const float* wsqs = wsq + stage * NC;
  const float4* gres = reinterpret_cast<const float4*>(res) + (size_t)row0 * 32;
  const float4* gw = reinterpret_cast<const float4*>(Ws);

  float best[16];
  int bidx[16];
  #pragma unroll
  for (int i = 0; i < 16; ++i) { best[i] = 3.4e38f; bidx[i] = 0; }

  for (int ct = 0; ct < 2; ++ct) {
    const int ctile = half * 512 + ct * 256;
    float acc[16][4];
    #pragma unroll
    for (int i = 0; i < 16; ++i)
      #pragma unroll
      for (int j = 0; j < 4; ++j) acc[i][j] = 0.f;

    for (int kc = 0; kc < 4; ++kc) {
      __syncthreads();   // previous compute phase done with LDS
      // stage A: 512 granules, 2 per thread
      #pragma unroll
      for (int it = 0; it < 2; ++it) {
        int fi = it * 256 + t;
        gload16(&gres[(fi >> 3) * 32 + kc * 8 + (fi & 7)], &A4[fi]);
      }
      // stage B: 2048 granules, 8 per thread (transposed layout == linear dest)
      #pragma unroll
      for (int it = 0; it < 8; ++it) {
        int fi = it * 256 + t;
        gload16(&gw[(size_t)(ctile + (fi & 255)) * 32 + kc * 8 + (fi >> 8)], &B4[fi]);
      }
      __syncthreads();   // drains vmcnt, data visible

      #pragma unroll 4
      for (int g = 0; g < 8; ++g) {
        float4 b0 = B4[g * 256 + lane];
        float4 b1 = B4[g * 256 + 64 + lane];
        float4 b2 = B4[g * 256 + 128 + lane];
        float4 b3 = B4[g * 256 + 192 + lane];
        const float4* pa = &A4[rg * 128 + g];
        #pragma unroll
        for (int i = 0; i < 16; ++i) {
          float4 a = pa[i * 8];
          acc[i][0] = fmaf(a.x, b0.x, acc[i][0]);
          acc[i][0] = fmaf(a.y, b0.y, acc[i][0]);
          acc[i][0] = fmaf(a.z, b0.z, acc[i][0]);
          acc[i][0] = fmaf(a.w, b0.w, acc[i][0]);
          acc[i][1] = fmaf(a.x, b1.x, acc[i][1]);
          acc[i][1] = fmaf(a.y, b1.y, acc[i][1]);
          acc[i][1] = fmaf(a.z, b1.z, acc[i][1]);
          acc[i][1] = fmaf(a.w, b1.w, acc[i][1]);
          acc[i][2] = fmaf(a.x, b2.x, acc[i][2]);
          acc[i][2] = fmaf(a.y, b2.y, acc[i][2]);
          acc[i][2] = fmaf(a.z, b2.z, acc[i][2]);
          acc[i][2] = fmaf(a.w, b2.w, acc[i][2]);
          acc[i][3] = fmaf(a.x, b3.x, acc[i][3]);
          acc[i][3] = fmaf(a.y, b3.y, acc[i][3]);
          acc[i][3] = fmaf(a.z, b3.z, acc[i][3]);
          acc[i][3] = fmaf(a.w, b3.w, acc[i][3]);
        }
      }
    }

    // epilogue: score = ||W||^2 - 2 r.W ; update per-row best (cols ascending)
    #pragma unroll
    for (int j = 0; j < 4; ++j) {
      int code = ctile + j * 64 + lane;
      float sq = wsqs[code];
      #pragma unroll
      for (int i = 0; i < 16; ++i) {
        float sc = fmaf(-2.f, acc[i][j], sq);
        if (sc < best[i]) { best[i] = sc; bidx[i] = code; }
      }
    }
  }

  // butterfly reduce across 64 lanes (all lanes share the same 16 rows)
  #pragma unroll
  for (int m = 1; m < 64; m <<= 1) {
    #pragma unroll
    for (int i = 0; i < 16; ++i) {
      float ov = __shfl_xor(best[i], m);
      int oi = __shfl_xor(bidx[i], m);
      if (ov < best[i] || (ov == best[i] && oi < bidx[i])) { best[i] = ov; bidx[i] = oi; }
    }
  }
  if (lane == 0) {
    #pragma unroll
    for (int i = 0; i < 16; ++i) {
      int row = row0 + rg * 16 + i;
      pbest[half * RR + row] = best[i];
      pidx[half * RR + row] = bidx[i];
    }
  }
}

// ---------------------------------------------------------------- merge halves
__global__ __launch_bounds__(256) void k_merge(
    const float* __restrict__ pbest, const int* __restrict__ pidx,
    int* __restrict__ idx_out, float* __restrict__ idxf_out)
{
  int r = blockIdx.x * 256 + threadIdx.x;
  float s0 = pbest[r], s1 = pbest[RR + r];
  int i0 = pidx[r], i1 = pidx[RR + r];
  int id = (s1 < s0) ? i1 : i0;   // tie -> i0 (always the smaller index)
  idx_out[r] = id;
  idxf_out[r] = (float)id;
}

// ---------------------------------------------------------------- per-row update
__global__ __launch_bounds__(256) void k_update(
    const float* __restrict__ res_cur, float* __restrict__ res_next,
    const float* __restrict__ W, const int* __restrict__ idx,
    float* __restrict__ counts, float* __restrict__ sums, int stage)
{
  int row = blockIdx.x * 8 + (threadIdx.x >> 5);
  int d4 = threadIdx.x & 31;
  int id = idx[row];
  const float4* rc = reinterpret_cast<const float4*>(res_cur + (size_t)row * DD);
  float4 r = rc[d4];
  const float4* wp = reinterpret_cast<const float4*>(W + ((size_t)stage * NC + id) * DD);
  float4 q = wp[d4];
  float4 o; o.x = r.x - q.x; o.y = r.y - q.y; o.z = r.z - q.z; o.w = r.w - q.w;
  reinterpret_cast<float4*>(res_next + (size_t)row * DD)[d4] = o;
  float* sb = &sums[(size_t)id * DD + d4 * 4];
  atomicAdd(sb + 0, r.x);
  atomicAdd(sb + 1, r.y);
  atomicAdd(sb + 2, r.z);
  atomicAdd(sb + 3, r.w);
  if (d4 == 0) atomicAdd(&counts[id], 1.0f);
}

// ---------------------------------------------------------------- threefry2x32 (JAX-exact)
__device__ __forceinline__ unsigned rotl32(unsigned v, int r) { return (v << r) | (v >> (32 - r)); }

__device__ void threefry2x32(unsigned ks0, unsigned ks1, unsigned x0, unsigned x1,
                             unsigned& o0, unsigned& o1)
{
  unsigned ks2 = ks0 ^ ks1 ^ 0x1BD11BDAu;
  x0 += ks0; x1 += ks1;
  x0 += x1; x1 = rotl32(x1, 13); x1 ^= x0;
  x0 += x1; x1 = rotl32(x1, 15); x1 ^= x0;
  x0 += x1; x1 = rotl32(x1, 26); x1 ^= x0;
  x0 += x1; x1 = rotl32(x1, 6);  x1 ^= x0;
  x0 += ks1; x1 += ks2 + 1u;
  x0 += x1; x1 = rotl32(x1, 17); x1 ^= x0;
  x0 += x1; x1 = rotl32(x1, 29); x1 ^= x0;
  x0 += x1; x1 = rotl32(x1, 16); x1 ^= x0;
  x0 += x1; x1 = rotl32(x1, 24); x1 ^= x0;
  x0 += ks2; x1 += ks0 + 2u;
  x0 += x1; x1 = rotl32(x1, 13); x1 ^= x0;
  x0 += x1; x1 = rotl32(x1, 15); x1 ^= x0;
  x0 += x1; x1 = rotl32(x1, 26); x1 ^= x0;
  x0 += x1; x1 = rotl32(x1, 6);  x1 ^= x0;
  x0 += ks0; x1 += ks1 + 3u;
  x0 += x1; x1 = rotl32(x1, 17); x1 ^= x0;
  x0 += x1; x1 = rotl32(x1, 29); x1 ^= x0;
  x0 += x1; x1 = rotl32(x1, 16); x1 ^= x0;
  x0 += x1; x1 = rotl32(x1, 24); x1 ^= x0;
  x0 += ks1; x1 += ks2 + 4u;
  x0 += x1; x1 = rotl32(x1, 13); x1 ^= x0;
  x0 += x1; x1 = rotl32(x1, 15); x1 ^= x0;
  x0 += x1; x1 = rotl32(x1, 26); x1 ^= x0;
  x0 += x1; x1 = rotl32(x1, 6);  x1 ^= x0;
  x0 += ks2; x1 += ks0 + 5u;
  o0 = x0; o1 = x1;
}

// ---------------------------------------------------------------- EMA / dead codes
__global__ __launch_bounds__(128) void k_finalize(
    const float* __restrict__ Ni_in, const float* __restrict__ mi_in,
    const float* __restrict__ counts, const float* __restrict__ sums,
    const float* __restrict__ res_cur,
    float* __restrict__ outNi, float* __restrict__ outmi, float* __restrict__ outW,
    int stage)
{
  const float ONEMG = (float)(1.0 - 0.99);
  int c = blockIdx.x, d = threadIdx.x;
  float cnt = counts[c];
  float ni = Ni_in[stage * NC + c] * GAMMA_F + cnt * ONEMG;
  float m = mi_in[((size_t)stage * NC + c) * DD + d] * GAMMA_F
          + sums[(size_t)c * DD + d] * ONEMG;
  float w = m / fmaxf(ni, 1e-8f);
  if (ni < 2.0f) {
    unsigned K0, K1, a0, a1, b0, b1, o0, o1;
    threefry2x32(0u, 42u, 0u, (unsigned)stage, K0, K1);   // fold_in
    threefry2x32(K0, K1, 0u, 2u, a0, a1);                 // split row 0
    threefry2x32(K0, K1, 1u, 3u, b0, b1);                 // split row 1
    unsigned bits;
    if (c < 512) { threefry2x32(a1, b1, (unsigned)c, (unsigned)(c + 512), o0, o1); bits = o0; }
    else         { threefry2x32(a1, b1, (unsigned)(c - 512), (unsigned)c, o0, o1); bits = o1; }
    int rid = (int)(bits & 32767u);
    w = res_cur[(size_t)rid * DD + d];
  }
  if (d == 0) outNi[stage * NC + c] = ni;
  size_t o = ((size_t)stage * NC + c) * DD + d;
  outmi[o] = m;
  outW[o] = w;
}

// ---------------------------------------------------------------- logits + loss partials
__global__ __launch_bounds__(256) void k_final(
    const float* __restrict__ data, const float* __restrict__ res,
    float* __restrict__ logits, float* __restrict__ partials)
{
  __shared__ float tile[32][33];
  __shared__ float wsum[4];
  int b = blockIdx.z, s0 = blockIdx.x << 5, d0 = blockIdx.y << 5;
  int tx = threadIdx.x, ty = threadIdx.y;
  #pragma unroll
  for (int r = 0; r < 32; r += 8)
    tile[ty + r][tx] = res[((size_t)b * SS + s0 + ty + r) * DD + d0 + tx];
  __syncthreads();
  float l = 0.f;
  #pragma unroll
  for (int r = 0; r < 32; r += 8) {
    int dv = d0 + ty + r, s = s0 + tx;
    size_t o = ((size_t)b * DD + dv) * SS + s;
    float rv = tile[tx][ty + r];
    logits[o] = data[o] - rv;         // == cur_y_t up to rounding
    l = fmaf(rv, rv, l);
  }
  #pragma unroll
  for (int m = 1; m < 64; m <<= 1) l += __shfl_xor(l, m);
  int lin = ty * 32 + tx;
  if ((lin & 63) == 0) wsum[lin >> 6] = l;
  __syncthreads();
  if (lin == 0) {
    int bl = (blockIdx.z * gridDim.y + blockIdx.y) * gridDim.x + blockIdx.x;
    partials[bl] = wsum[0] + wsum[1] + wsum[2] + wsum[3];
  }
}

__global__ __launch_bounds__(1024) void k_loss_reduce(
    const float* __restrict__ partials, float* __restrict__ loss)
{
  __shared__ float ws[16];
  int t = threadIdx.x;
  float s = partials[t] + partials[t + 1024] + partials[t + 2048] + partials[t + 3072];
  #pragma unroll
  for (int m = 1; m < 64; m <<= 1) s += __shfl_xor(s, m);
  if ((t & 63) == 0) ws[t >> 6] = s;
  __syncthreads();
  if (t < 16) {
    float v = ws[t];
    #pragma unroll
    for (int m = 1; m < 16; m <<= 1) v += __shfl_xor(v, m);
    if (t == 0) loss[0] = v * (1.0f / 4194304.0f);
  }
}

// ---------------------------------------------------------------- launch
extern "C" void kernel_launch(void* const* d_in, const int* in_sizes, int n_in,
                              void* d_out, int out_size, void* d_ws, size_t ws_size,
                              hipStream_t stream)
{
  (void)in_sizes; (void)n_in; (void)out_size; (void)ws_size;
  const float* data = (const float*)d_in[0];
  const float* W    = (const float*)d_in[1];
  const float* Ni   = (const float*)d_in[2];
  const float* mi   = (const float*)d_in[3];

  float* out        = (float*)d_out;
  float* out_logits = out;
  float* out_loss   = out + (size_t)BB * DD * SS;       // 4194304
  float* out_idx    = out_loss + 1;
  float* out_Ni     = out_idx + (size_t)NQ * RR;        // +262144
  float* out_mi     = out_Ni + (size_t)NQ * NC;         // +8192
  float* out_W      = out_mi + (size_t)NQ * NC * DD;    // +1048576

  float* resA     = (float*)d_ws;
  float* resB     = resA + (size_t)RR * DD;
  int*   idxw     = (int*)(resB + (size_t)RR * DD);
  float* counts   = (float*)(idxw + RR);
  float* sums     = counts + NC;
  float* wsq      = sums + (size_t)NC * DD;
  float* partials = wsq + NQ * NC;
  float* pbest    = partials + 4096;
  int*   pidx     = (int*)(pbest + 2 * (size_t)RR);

  k_transpose_in<<<dim3(SS / 32, DD / 32, BB), dim3(32, 8), 0, stream>>>(data, resA);
  k_wsq<<<(NQ * NC + 255) / 256, 256, 0, stream>>>(W, wsq);

  float* cur = resA;
  float* nxt = resB;
  for (int i = 0; i < NQ; ++i) {
    hipMemsetAsync(counts, 0, (NC + (size_t)NC * DD) * sizeof(float), stream);
    k_argmin<<<dim3(RR / 64, 2), 256, 0, stream>>>(cur, W, wsq, pbest, pidx, i);
    k_merge<<<RR / 256, 256, 0, stream>>>(pbest, pidx, idxw, out_idx + (size_t)i * RR);
    k_update<<<RR / 8, 256, 0, stream>>>(cur, nxt, W, idxw, counts, sums, i);
    k_finalize<<<NC, 128, 0, stream>>>(Ni, mi, counts, sums, cur, out_Ni, out_mi, out_W, i);
    float* tmp = cur; cur = nxt; nxt = tmp;
  }

  k_final<<<dim3(SS / 32, DD / 32, BB), dim3(32, 8), 0, stream>>>(data, cur, out_logits, partials);
  k_loss_reduce<<<1, 1024, 0, stream>>>(partials, out_loss);
}

// Round 6
// 2006.988 us; speedup vs baseline: 1.1857x; 1.1441x over previous
//
#include <hip/hip_runtime.h>
#include <hip/hip_bf16.h>

#define NQ 8
#define NC 1024
#define DD 128
#define BB 16
#define SS 2048
#define RR (BB * SS)   // 32768 rows
#define GAMMA_F 0.99f
#define TAU 0.03f

typedef __attribute__((ext_vector_type(8))) short bf16x8;
typedef __attribute__((ext_vector_type(4))) float f32x4;

typedef __attribute__((address_space(3))) void lds_void;
typedef const __attribute__((address_space(1))) void g1_void;
__device__ __forceinline__ void gload16(const void* g, void* l) {
  __builtin_amdgcn_global_load_lds((g1_void*)g, (lds_void*)l, 16, 0, 0);
}

__device__ __forceinline__ ushort f2bf(float x) {
  __hip_bfloat16 b = __float2bfloat16(x);
  return *reinterpret_cast<ushort*>(&b);
}
__device__ __forceinline__ float bf2f(ushort u) {
  unsigned v = ((unsigned)u) << 16;
  return *reinterpret_cast<float*>(&v);
}

// 4-bit LDS granule swizzle: spreads 16 consecutive rows over all 8 bank-quads
__device__ __forceinline__ int swz(int r) {
  return ((r & 7) << 2) | ((r >> 3) & 1);
}

// ---------------------------------------------------------------- transpose in
__global__ __launch_bounds__(256) void k_transpose_in(
    const float* __restrict__ data, float* __restrict__ res)
{
  __shared__ float tile[32][33];
  int b = blockIdx.z;
  int s0 = blockIdx.x << 5, d0 = blockIdx.y << 5;
  int tx = threadIdx.x, ty = threadIdx.y;   // (32,8)
  #pragma unroll
  for (int r = 0; r < 32; r += 8)
    tile[ty + r][tx] = data[((size_t)b * DD + d0 + ty + r) * SS + s0 + tx];
  __syncthreads();
  #pragma unroll
  for (int r = 0; r < 32; r += 8)
    res[((size_t)b * SS + s0 + ty + r) * DD + d0 + tx] = tile[tx][ty + r];
}

// ---------------------------------------------------------------- ||W||^2
__global__ void k_wsq(const float* __restrict__ W, float* __restrict__ wsq)
{
  int c = blockIdx.x * blockDim.x + threadIdx.x;
  if (c >= NQ * NC) return;
  const float4* p = reinterpret_cast<const float4*>(W + (size_t)c * DD);
  float s = 0.f;
  #pragma unroll 8
  for (int k = 0; k < DD / 4; ++k) {
    float4 v = p[k];
    s += v.x * v.x + v.y * v.y + v.z * v.z + v.w * v.w;
  }
  wsq[c] = s;
}

// ---------------------------------------------------------------- bf16 hi/lo split
// global granule (row, c) at base + (row*32 + c)*8 ushorts, c = kgq*2 + h, kgq in [0,16)
__global__ __launch_bounds__(256) void k_split(
    const float* __restrict__ src, ushort* __restrict__ dst)
{
  int fi = blockIdx.x * 256 + threadIdx.x;
  const float4* sp = reinterpret_cast<const float4*>(src) + (size_t)fi * 2;
  float4 a = sp[0], b = sp[1];
  ushort4 h0, h1, l0, l1;
  h0.x = f2bf(a.x); l0.x = f2bf(a.x - bf2f(h0.x));
  h0.y = f2bf(a.y); l0.y = f2bf(a.y - bf2f(h0.y));
  h0.z = f2bf(a.z); l0.z = f2bf(a.z - bf2f(h0.z));
  h0.w = f2bf(a.w); l0.w = f2bf(a.w - bf2f(h0.w));
  h1.x = f2bf(b.x); l1.x = f2bf(b.x - bf2f(h1.x));
  h1.y = f2bf(b.y); l1.y = f2bf(b.y - bf2f(h1.y));
  h1.z = f2bf(b.z); l1.z = f2bf(b.z - bf2f(h1.z));
  h1.w = f2bf(b.w); l1.w = f2bf(b.w - bf2f(h1.w));
  ushort4* dp = reinterpret_cast<ushort4*>(dst + (size_t)fi * 16);
  dp[0] = h0; dp[1] = h1; dp[2] = l0; dp[3] = l1;
}

// ---------------------------------------------------------------- MFMA argmin (full 1024 codes)
// 512 thr = 8 waves (wm=w>>1 rows, wn=w&1 cols). Block: 128 rows x 1024 codes.
// A (128 rows x K128 x hi/lo) resident in LDS 64KB; B staged per 128-code tile 64KB.
// 3-term split hh + lh + hl (ll term < 1.2e-3, inside TAU margin).
__global__ __launch_bounds__(512, 1) void k_argmin(
    const ushort* __restrict__ res_hl, const ushort* __restrict__ w_hl,
    const float* __restrict__ wsq,
    int* __restrict__ idxw, float* __restrict__ idxf,
    int* __restrict__ count, int* __restrict__ fb_count,
    int* __restrict__ fb_list, int stage)
{
  __shared__ bf16x8 Ash[4096];   // 64 KiB
  __shared__ bf16x8 Bsh[4096];   // 64 KiB
  __shared__ float Lm1[2][128], Lm2[2][128];
  __shared__ int   Li1[2][128];

  const int t = threadIdx.x;
  const int l = t & 63;
  const int w = t >> 6;
  const int wm = w >> 1;         // 0..3 (row group of 32)
  const int wn = w & 1;          // 0..1 (col half of 64 within 128-tile)
  const int row0 = blockIdx.x * 128;
  const int l15 = l & 15, kg = l >> 4;
  const float* wsqs = wsq + stage * NC;

  // stage A (once): 4096 granules
  #pragma unroll
  for (int it = 0; it < 8; ++it) {
    int fi = it * 512 + t;
    int r = fi >> 5, sc = fi & 31;
    gload16(res_hl + ((size_t)(row0 + r) * 32 + (sc ^ swz(r))) * 8, &Ash[fi]);
  }

  float m1[2][4], m2[2][4];
  int i1[2][4];
  #pragma unroll
  for (int mf = 0; mf < 2; ++mf)
    #pragma unroll
    for (int rg = 0; rg < 4; ++rg) { m1[mf][rg] = 3.4e38f; m2[mf][rg] = 3.4e38f; i1[mf][rg] = 0; }

  for (int ct = 0; ct < 8; ++ct) {
    if (ct > 0) __syncthreads();   // done computing with previous Bsh
    #pragma unroll
    for (int it = 0; it < 8; ++it) {
      int fi = it * 512 + t;
      int cr = fi >> 5, sc = fi & 31;
      gload16(w_hl + ((size_t)(stage * NC + ct * 128 + cr) * 32 + (sc ^ swz(cr))) * 8, &Bsh[fi]);
    }
    __syncthreads();   // drains vmcnt (A on ct==0, B always)

    f32x4 zero = {0.f, 0.f, 0.f, 0.f};
    f32x4 acc[2][4];
    #pragma unroll
    for (int mf = 0; mf < 2; ++mf)
      #pragma unroll
      for (int nf = 0; nf < 4; ++nf) acc[mf][nf] = zero;

    #pragma unroll
    for (int ks = 0; ks < 4; ++ks) {
      const int ch = ks * 8 + kg * 2;
      bf16x8 ah[2], al[2];
      #pragma unroll
      for (int mf = 0; mf < 2; ++mf) {
        int r = wm * 32 + mf * 16 + l15;
        ah[mf] = Ash[r * 32 + (ch ^ swz(r))];
        al[mf] = Ash[r * 32 + ((ch + 1) ^ swz(r))];
      }
      #pragma unroll
      for (int nf = 0; nf < 4; ++nf) {
        int cr = wn * 64 + nf * 16 + l15;
        bf16x8 bh = Bsh[cr * 32 + (ch ^ swz(cr))];
        bf16x8 bl = Bsh[cr * 32 + ((ch + 1) ^ swz(cr))];
        #pragma unroll
        for (int mf = 0; mf < 2; ++mf) {
          f32x4 cc = acc[mf][nf];
          cc = __builtin_amdgcn_mfma_f32_16x16x32_bf16(ah[mf], bh, cc, 0, 0, 0);
          cc = __builtin_amdgcn_mfma_f32_16x16x32_bf16(al[mf], bh, cc, 0, 0, 0);
          cc = __builtin_amdgcn_mfma_f32_16x16x32_bf16(ah[mf], bl, cc, 0, 0, 0);
          acc[mf][nf] = cc;
        }
      }
    }

    // epilogue: fold this ct's scores into running per-lane (m1, m2, i1)
    #pragma unroll
    for (int nf = 0; nf < 4; ++nf) {
      int code = ct * 128 + wn * 64 + nf * 16 + l15;
      float sq = wsqs[code];
      #pragma unroll
      for (int mf = 0; mf < 2; ++mf)
        #pragma unroll
        for (int rg = 0; rg < 4; ++rg) {
          float s = fmaf(-2.f, acc[mf][nf][rg], sq);
          if (s < m1[mf][rg]) { m2[mf][rg] = m1[mf][rg]; m1[mf][rg] = s; i1[mf][rg] = code; }
          else if (s < m2[mf][rg]) m2[mf][rg] = s;
        }
    }
  }

  // butterfly over the 16 col-classes (lanes sharing l>>4 = same row)
  #pragma unroll
  for (int mk = 1; mk <= 8; mk <<= 1) {
    #pragma unroll
    for (int mf = 0; mf < 2; ++mf)
      #pragma unroll
      for (int rg = 0; rg < 4; ++rg) {
        float om1 = __shfl_xor(m1[mf][rg], mk);
        int   oi  = __shfl_xor(i1[mf][rg], mk);
        float om2 = __shfl_xor(m2[mf][rg], mk);
        bool bwin = (om1 < m1[mf][rg]) || (om1 == m1[mf][rg] && oi < i1[mf][rg]);
        float lose = bwin ? m1[mf][rg] : om1;
        m2[mf][rg] = fminf(fminf(m2[mf][rg], om2), lose);
        if (bwin) { m1[mf][rg] = om1; i1[mf][rg] = oi; }
      }
  }
  if (l15 == 0) {
    #pragma unroll
    for (int mf = 0; mf < 2; ++mf)
      #pragma unroll
      for (int rg = 0; rg < 4; ++rg) {
        int rl = wm * 32 + mf * 16 + kg * 4 + rg;
        Lm1[wn][rl] = m1[mf][rg];
        Lm2[wn][rl] = m2[mf][rg];
        Li1[wn][rl] = i1[mf][rg];
      }
  }
  __syncthreads();

  if (t < 128) {
    float a1 = Lm1[0][t], a2 = Lm2[0][t];
    int ai = Li1[0][t];
    float b1 = Lm1[1][t], b2 = Lm2[1][t];
    int bi = Li1[1][t];
    bool bwin = (b1 < a1) || (b1 == a1 && bi < ai);
    float lose = bwin ? a1 : b1;
    float gm1 = bwin ? b1 : a1;
    int gi = bwin ? bi : ai;
    float gm2 = fminf(fminf(a2, b2), lose);
    int row = row0 + t;
    if (gm2 - gm1 > TAU) {
      idxw[row] = gi;
      idxf[row] = (float)gi;
      atomicAdd(&count[gi], 1);
    } else {
      int p = atomicAdd(fb_count, 1);
      fb_list[p] = row;
    }
  }
}

// ---------------------------------------------------------------- exact fp32 fallback
__global__ __launch_bounds__(256) void k_fallback(
    const float* __restrict__ res, const float* __restrict__ W,
    const float* __restrict__ wsq, const int* __restrict__ fb_count,
    const int* __restrict__ fb_list,
    int* __restrict__ idxw, float* __restrict__ idxf,
    int* __restrict__ count, int stage)
{
  __shared__ float rr[128];
  __shared__ float sv[256];
  __shared__ int   si[256];
  int n = *fb_count;
  int t = threadIdx.x;
  for (int b = blockIdx.x; b < n; b += gridDim.x) {
    int row = fb_list[b];
    __syncthreads();
    if (t < 128) rr[t] = res[(size_t)row * DD + t];
    __syncthreads();
    float bm = 3.4e38f; int bi = 0;
    #pragma unroll
    for (int j = 0; j < 4; ++j) {
      int c = t + j * 256;
      const float4* wp = reinterpret_cast<const float4*>(W + ((size_t)stage * NC + c) * DD);
      float dot = 0.f;
      #pragma unroll 8
      for (int k = 0; k < 32; ++k) {
        float4 wv = wp[k];
        dot = fmaf(rr[4 * k + 0], wv.x, dot);
        dot = fmaf(rr[4 * k + 1], wv.y, dot);
        dot = fmaf(rr[4 * k + 2], wv.z, dot);
        dot = fmaf(rr[4 * k + 3], wv.w, dot);
      }
      float s = fmaf(-2.f, dot, wsq[stage * NC + c]);
      if (s < bm || (s == bm && c < bi)) { bm = s; bi = c; }
    }
    sv[t] = bm; si[t] = bi;
    __syncthreads();
    for (int sft = 128; sft > 0; sft >>= 1) {
      if (t < sft) {
        float ov = sv[t + sft]; int oi = si[t + sft];
        if (ov < sv[t] || (ov == sv[t] && oi < si[t])) { sv[t] = ov; si[t] = oi; }
      }
      __syncthreads();
    }
    if (t == 0) {
      int win = si[0];
      idxw[row] = win;
      idxf[row] = (float)win;
      atomicAdd(&count[win], 1);
    }
  }
}

// ---------------------------------------------------------------- prefix scan + pos reset
__global__ __launch_bounds__(1024) void k_scan(
    const int* __restrict__ count, int* __restrict__ offs, int* __restrict__ pos)
{
  __shared__ int sc[1024];
  int t = threadIdx.x;
  sc[t] = count[t];
  __syncthreads();
  for (int off = 1; off < 1024; off <<= 1) {
    int v = (t >= off) ? sc[t - off] : 0;
    __syncthreads();
    sc[t] += v;
    __syncthreads();
  }
  offs[t + 1] = sc[t];
  if (t == 0) offs[0] = 0;
  pos[t] = 0;
}

// ---------------------------------------------------------------- CSR scatter
__global__ __launch_bounds__(256) void k_scatter(
    const int* __restrict__ idxw, const int* __restrict__ offs,
    int* __restrict__ pos, int* __restrict__ rows_sorted)
{
  int r = blockIdx.x * 256 + threadIdx.x;
  int c = idxw[r];
  int slot = offs[c] + atomicAdd(&pos[c], 1);
  rows_sorted[slot] = r;
}

// ---------------------------------------------------------------- threefry2x32 (JAX-exact)
__device__ __forceinline__ unsigned rotl32(unsigned v, int r) { return (v << r) | (v >> (32 - r)); }

__device__ void threefry2x32(unsigned ks0, unsigned ks1, unsigned x0, unsigned x1,
                             unsigned& o0, unsigned& o1)
{
  unsigned ks2 = ks0 ^ ks1 ^ 0x1BD11BDAu;
  x0 += ks0; x1 += ks1;
  x0 += x1; x1 = rotl32(x1, 13); x1 ^= x0;
  x0 += x1; x1 = rotl32(x1, 15); x1 ^= x0;
  x0 += x1; x1 = rotl32(x1, 26); x1 ^= x0;
  x0 += x1; x1 = rotl32(x1, 6);  x1 ^= x0;
  x0 += ks1; x1 += ks2 + 1u;
  x0 += x1; x1 = rotl32(x1, 17); x1 ^= x0;
  x0 += x1; x1 = rotl32(x1, 29); x1 ^= x0;
  x0 += x1; x1 = rotl32(x1, 16); x1 ^= x0;
  x0 += x1; x1 = rotl32(x1, 24); x1 ^= x0;
  x0 += ks2; x1 += ks0 + 2u;
  x0 += x1; x1 = rotl32(x1, 13); x1 ^= x0;
  x0 += x1; x1 = rotl32(x1, 15); x1 ^= x0;
  x0 += x1; x1 = rotl32(x1, 26); x1 ^= x0;
  x0 += x1; x1 = rotl32(x1, 6);  x1 ^= x0;
  x0 += ks0; x1 += ks1 + 3u;
  x0 += x1; x1 = rotl32(x1, 17); x1 ^= x0;
  x0 += x1; x1 = rotl32(x1, 29); x1 ^= x0;
  x0 += x1; x1 = rotl32(x1, 16); x1 ^= x0;
  x0 += x1; x1 = rotl32(x1, 24); x1 ^= x0;
  x0 += ks1; x1 += ks2 + 4u;
  x0 += x1; x1 = rotl32(x1, 13); x1 ^= x0;
  x0 += x1; x1 = rotl32(x1, 15); x1 ^= x0;
  x0 += x1; x1 = rotl32(x1, 26); x1 ^= x0;
  x0 += x1; x1 = rotl32(x1, 6);  x1 ^= x0;
  x0 += ks2; x1 += ks0 + 5u;
  o0 = x0; o1 = x1;
}

// ---------------------------------------------------------------- EMA / dead codes (CSR gather)
__global__ __launch_bounds__(128) void k_finalize(
    const float* __restrict__ Ni_in, const float* __restrict__ mi_in,
    const int* __restrict__ count, const int* __restrict__ offs,
    const int* __restrict__ rows_sorted, const float* __restrict__ res_cur,
    float* __restrict__ outNi, float* __restrict__ outmi, float* __restrict__ outW,
    int stage)
{
  const float ONEMG = (float)(1.0 - 0.99);
  int c = blockIdx.x, d = threadIdx.x;
  int cnt = count[c];
  int base = offs[c];
  float sum = 0.f;
  for (int j = 0; j < cnt; ++j)
    sum += res_cur[(size_t)rows_sorted[base + j] * DD + d];
  float ni = Ni_in[stage * NC + c] * GAMMA_F + (float)cnt * ONEMG;
  float mm = mi_in[((size_t)stage * NC + c) * DD + d] * GAMMA_F + sum * ONEMG;
  float w = mm / fmaxf(ni, 1e-8f);
  if (ni < 2.0f) {
    unsigned K0, K1, a0, a1, b0, b1, o0, o1;
    threefry2x32(0u, 42u, 0u, (unsigned)stage, K0, K1);
    threefry2x32(K0, K1, 0u, 2u, a0, a1);
    threefry2x32(K0, K1, 1u, 3u, b0, b1);
    unsigned bits;
    if (c < 512) { threefry2x32(a1, b1, (unsigned)c, (unsigned)(c + 512), o0, o1); bits = o0; }
    else         { threefry2x32(a1, b1, (unsigned)(c - 512), (unsigned)c, o0, o1); bits = o1; }
    int rid = (int)(bits & 32767u);
    w = res_cur[(size_t)rid * DD + d];
  }
  if (d == 0) outNi[stage * NC + c] = ni;
  size_t o = ((size_t)stage * NC + c) * DD + d;
  outmi[o] = mm;
  outW[o] = w;
}

// ---------------------------------------------------------------- residual update (in-place) + bf16 split
__global__ __launch_bounds__(256) void k_update(
    float* __restrict__ res, const float* __restrict__ W,
    const int* __restrict__ idx, ushort* __restrict__ res_hl, int stage)
{
  int row = blockIdx.x * 8 + (threadIdx.x >> 5);
  int d4 = threadIdx.x & 31;
  int id = idx[row];
  float4 r = reinterpret_cast<const float4*>(res + (size_t)row * DD)[d4];
  float4 q = reinterpret_cast<const float4*>(W + ((size_t)stage * NC + id) * DD)[d4];
  float4 o;
  o.x = r.x - q.x; o.y = r.y - q.y; o.z = r.z - q.z; o.w = r.w - q.w;
  reinterpret_cast<float4*>(res + (size_t)row * DD)[d4] = o;
  ushort4 hi, lo;
  hi.x = f2bf(o.x); lo.x = f2bf(o.x - bf2f(hi.x));
  hi.y = f2bf(o.y); lo.y = f2bf(o.y - bf2f(hi.y));
  hi.z = f2bf(o.z); lo.z = f2bf(o.z - bf2f(hi.z));
  hi.w = f2bf(o.w); lo.w = f2bf(o.w - bf2f(hi.w));
  size_t g = ((size_t)row * 16 + (d4 >> 1)) * 2;
  *reinterpret_cast<ushort4*>(res_hl + g * 8 + (d4 & 1) * 4) = hi;
  *reinterpret_cast<ushort4*>(res_hl + (g + 1) * 8 + (d4 & 1) * 4) = lo;
}

// ---------------------------------------------------------------- logits + loss partials
__global__ __launch_bounds__(256) void k_final(
    const float* __restrict__ data, const float* __restrict__ res,
    float* __restrict__ logits, float* __restrict__ partials)
{
  __shared__ float tile[32][33];
  __shared__ float wsum[4];
  int b = blockIdx.z, s0 = blockIdx.x << 5, d0 = blockIdx.y << 5;
  int tx = threadIdx.x, ty = threadIdx.y;
  #pragma unroll
  for (int r = 0; r < 32; r += 8)
    tile[ty + r][tx] = res[((size_t)b * SS + s0 + ty + r) * DD + d0 + tx];
  __syncthreads();
  float l = 0.f;
  #pragma unroll
  for (int r = 0; r < 32; r += 8) {
    int dv = d0 + ty + r, s = s0 + tx;
    size_t o = ((size_t)b * DD + dv) * SS + s;
    float rv = tile[tx][ty + r];
    logits[o] = data[o] - rv;
    l = fmaf(rv, rv, l);
  }
  #pragma unroll
  for (int m = 1; m < 64; m <<= 1) l += __shfl_xor(l, m);
  int lin = ty * 32 + tx;
  if ((lin & 63) == 0) wsum[lin >> 6] = l;
  __syncthreads();
  if (lin == 0) {
    int bl = (blockIdx.z * gridDim.y + blockIdx.y) * gridDim.x + blockIdx.x;
    partials[bl] = wsum[0] + wsum[1] + wsum[2] + wsum[3];
  }
}

__global__ __launch_bounds__(1024) void k_loss_reduce(
    const float* __restrict__ partials, float* __restrict__ loss)
{
  __shared__ float ws[16];
  int t = threadIdx.x;
  float s = partials[t] + partials[t + 1024] + partials[t + 2048] + partials[t + 3072];
  #pragma unroll
  for (int m = 1; m < 64; m <<= 1) s += __shfl_xor(s, m);
  if ((t & 63) == 0) ws[t >> 6] = s;
  __syncthreads();
  if (t < 16) {
    float v = ws[t];
    #pragma unroll
    for (int m = 1; m < 16; m <<= 1) v += __shfl_xor(v, m);
    if (t == 0) loss[0] = v * (1.0f / 4194304.0f);
  }
}

// ---------------------------------------------------------------- launch
extern "C" void kernel_launch(void* const* d_in, const int* in_sizes, int n_in,
                              void* d_out, int out_size, void* d_ws, size_t ws_size,
                              hipStream_t stream)
{
  (void)in_sizes; (void)n_in; (void)out_size; (void)ws_size;
  const float* data = (const float*)d_in[0];
  const float* W    = (const float*)d_in[1];
  const float* Ni   = (const float*)d_in[2];
  const float* mi   = (const float*)d_in[3];

  float* out        = (float*)d_out;
  float* out_logits = out;
  float* out_loss   = out + (size_t)BB * DD * SS;
  float* out_idx    = out_loss + 1;
  float* out_Ni     = out_idx + (size_t)NQ * RR;
  float* out_mi     = out_Ni + (size_t)NQ * NC;
  float* out_W      = out_mi + (size_t)NQ * NC * DD;

  char* wp = (char*)d_ws;
  float*  resA        = (float*)wp;   wp += (size_t)RR * DD * 4;       // 16.78 MB
  ushort* res_hl      = (ushort*)wp;  wp += (size_t)RR * DD * 4;       // 16.78 MB
  ushort* w_hl        = (ushort*)wp;  wp += (size_t)NQ * NC * DD * 4;  // 4.19 MB
  float*  wsq         = (float*)wp;   wp += (size_t)NQ * NC * 4;
  int*    idxw        = (int*)wp;     wp += (size_t)RR * 4;
  int*    fb_list     = (int*)wp;     wp += (size_t)RR * 4;
  int*    rows_sorted = (int*)wp;     wp += (size_t)RR * 4;
  int*    count       = (int*)wp;     wp += (size_t)1025 * 4;          // count[1024] + fb_count
  int*    fb_count    = count + 1024;
  int*    pos         = (int*)wp;     wp += (size_t)NC * 4;
  int*    offs        = (int*)wp;     wp += (size_t)(NC + 1) * 4;
  float*  partials    = (float*)wp;   wp += (size_t)4096 * 4;

  k_transpose_in<<<dim3(SS / 32, DD / 32, BB), dim3(32, 8), 0, stream>>>(data, resA);
  k_split<<<RR * 16 / 256, 256, 0, stream>>>(resA, res_hl);
  k_wsq<<<(NQ * NC + 255) / 256, 256, 0, stream>>>(W, wsq);
  k_split<<<NQ * NC * 16 / 256, 256, 0, stream>>>(W, w_hl);

  for (int i = 0; i < NQ; ++i) {
    hipMemsetAsync(count, 0, 1025 * sizeof(int), stream);
    k_argmin<<<RR / 128, 512, 0, stream>>>(res_hl, w_hl, wsq, idxw,
                                           out_idx + (size_t)i * RR,
                                           count, fb_count, fb_list, i);
    k_fallback<<<512, 256, 0, stream>>>(resA, W, wsq, fb_count, fb_list,
                                        idxw, out_idx + (size_t)i * RR, count, i);
    k_scan<<<1, 1024, 0, stream>>>(count, offs, pos);
    k_scatter<<<RR / 256, 256, 0, stream>>>(idxw, offs, pos, rows_sorted);
    k_finalize<<<NC, 128, 0, stream>>>(Ni, mi, count, offs, rows_sorted, resA,
                                       out_Ni, out_mi, out_W, i);
    k_update<<<RR / 8, 256, 0, stream>>>(resA, W, idxw, res_hl, i);
  }

  k_final<<<dim3(SS / 32, DD / 32, BB), dim3(32, 8), 0, stream>>>(data, resA, out_logits, partials);
  k_loss_reduce<<<1, 1024, 0, stream>>>(partials, out_loss);
}

// Round 7
// 904.038 us; speedup vs baseline: 2.6322x; 2.2200x over previous
//
#include <hip/hip_runtime.h>
#include <hip/hip_bf16.h>

#define NQ 8
#define NC 1024
#define DD 128
#define BB 16
#define SS 2048
#define RR (BB * SS)   // 32768 rows
#define GAMMA_F 0.99f
#define TAU 0.03f

typedef __attribute__((ext_vector_type(8))) short bf16x8;
typedef __attribute__((ext_vector_type(4))) float f32x4;

typedef __attribute__((address_space(3))) void lds_void;
typedef const __attribute__((address_space(1))) void g1_void;
__device__ __forceinline__ void gload16(const void* g, void* l) {
  __builtin_amdgcn_global_load_lds((g1_void*)g, (lds_void*)l, 16, 0, 0);
}

__device__ __forceinline__ ushort f2bf(float x) {
  __hip_bfloat16 b = __float2bfloat16(x);
  return *reinterpret_cast<ushort*>(&b);
}
__device__ __forceinline__ float bf2f(ushort u) {
  unsigned v = ((unsigned)u) << 16;
  return *reinterpret_cast<float*>(&v);
}

// 4-bit LDS granule swizzle: spreads 16 consecutive rows over all 8 bank-quads
__device__ __forceinline__ int swz(int r) {
  return ((r & 7) << 2) | ((r >> 3) & 1);
}

// ---------------------------------------------------------------- transpose in
__global__ __launch_bounds__(256) void k_transpose_in(
    const float* __restrict__ data, float* __restrict__ res)
{
  __shared__ float tile[32][33];
  int b = blockIdx.z;
  int s0 = blockIdx.x << 5, d0 = blockIdx.y << 5;
  int tx = threadIdx.x, ty = threadIdx.y;   // (32,8)
  #pragma unroll
  for (int r = 0; r < 32; r += 8)
    tile[ty + r][tx] = data[((size_t)b * DD + d0 + ty + r) * SS + s0 + tx];
  __syncthreads();
  #pragma unroll
  for (int r = 0; r < 32; r += 8)
    res[((size_t)b * SS + s0 + ty + r) * DD + d0 + tx] = tile[tx][ty + r];
}

// ---------------------------------------------------------------- ||W||^2
__global__ void k_wsq(const float* __restrict__ W, float* __restrict__ wsq)
{
  int c = blockIdx.x * blockDim.x + threadIdx.x;
  if (c >= NQ * NC) return;
  const float4* p = reinterpret_cast<const float4*>(W + (size_t)c * DD);
  float s = 0.f;
  #pragma unroll 8
  for (int k = 0; k < DD / 4; ++k) {
    float4 v = p[k];
    s += v.x * v.x + v.y * v.y + v.z * v.z + v.w * v.w;
  }
  wsq[c] = s;
}

// ---------------------------------------------------------------- bf16 hi/lo split
__global__ __launch_bounds__(256) void k_split(
    const float* __restrict__ src, ushort* __restrict__ dst)
{
  int fi = blockIdx.x * 256 + threadIdx.x;
  const float4* sp = reinterpret_cast<const float4*>(src) + (size_t)fi * 2;
  float4 a = sp[0], b = sp[1];
  ushort4 h0, h1, l0, l1;
  h0.x = f2bf(a.x); l0.x = f2bf(a.x - bf2f(h0.x));
  h0.y = f2bf(a.y); l0.y = f2bf(a.y - bf2f(h0.y));
  h0.z = f2bf(a.z); l0.z = f2bf(a.z - bf2f(h0.z));
  h0.w = f2bf(a.w); l0.w = f2bf(a.w - bf2f(h0.w));
  h1.x = f2bf(b.x); l1.x = f2bf(b.x - bf2f(h1.x));
  h1.y = f2bf(b.y); l1.y = f2bf(b.y - bf2f(h1.y));
  h1.z = f2bf(b.z); l1.z = f2bf(b.z - bf2f(h1.z));
  h1.w = f2bf(b.w); l1.w = f2bf(b.w - bf2f(h1.w));
  ushort4* dp = reinterpret_cast<ushort4*>(dst + (size_t)fi * 16);
  dp[0] = h0; dp[1] = h1; dp[2] = l0; dp[3] = l1;
}

// ---------------------------------------------------------------- MFMA argmin (full 1024 codes)
__global__ __launch_bounds__(512, 1) void k_argmin(
    const ushort* __restrict__ res_hl, const ushort* __restrict__ w_hl,
    const float* __restrict__ wsq,
    int* __restrict__ idxw, float* __restrict__ idxf,
    int* __restrict__ count, int* __restrict__ fb_count,
    int* __restrict__ fb_list, int stage)
{
  __shared__ bf16x8 Ash[4096];   // 64 KiB
  __shared__ bf16x8 Bsh[4096];   // 64 KiB
  __shared__ float Lm1[2][128], Lm2[2][128];
  __shared__ int   Li1[2][128];

  const int t = threadIdx.x;
  const int l = t & 63;
  const int w = t >> 6;
  const int wm = w >> 1;         // 0..3 (row group of 32)
  const int wn = w & 1;          // 0..1 (col half of 64 within 128-tile)
  const int row0 = blockIdx.x * 128;
  const int l15 = l & 15, kg = l >> 4;
  const float* wsqs = wsq + stage * NC;

  #pragma unroll
  for (int it = 0; it < 8; ++it) {
    int fi = it * 512 + t;
    int r = fi >> 5, sc = fi & 31;
    gload16(res_hl + ((size_t)(row0 + r) * 32 + (sc ^ swz(r))) * 8, &Ash[fi]);
  }

  float m1[2][4], m2[2][4];
  int i1[2][4];
  #pragma unroll
  for (int mf = 0; mf < 2; ++mf)
    #pragma unroll
    for (int rg = 0; rg < 4; ++rg) { m1[mf][rg] = 3.4e38f; m2[mf][rg] = 3.4e38f; i1[mf][rg] = 0; }

  for (int ct = 0; ct < 8; ++ct) {
    if (ct > 0) __syncthreads();
    #pragma unroll
    for (int it = 0; it < 8; ++it) {
      int fi = it * 512 + t;
      int cr = fi >> 5, sc = fi & 31;
      gload16(w_hl + ((size_t)(stage * NC + ct * 128 + cr) * 32 + (sc ^ swz(cr))) * 8, &Bsh[fi]);
    }
    __syncthreads();

    f32x4 zero = {0.f, 0.f, 0.f, 0.f};
    f32x4 acc[2][4];
    #pragma unroll
    for (int mf = 0; mf < 2; ++mf)
      #pragma unroll
      for (int nf = 0; nf < 4; ++nf) acc[mf][nf] = zero;

    #pragma unroll
    for (int ks = 0; ks < 4; ++ks) {
      const int ch = ks * 8 + kg * 2;
      bf16x8 ah[2], al[2];
      #pragma unroll
      for (int mf = 0; mf < 2; ++mf) {
        int r = wm * 32 + mf * 16 + l15;
        ah[mf] = Ash[r * 32 + (ch ^ swz(r))];
        al[mf] = Ash[r * 32 + ((ch + 1) ^ swz(r))];
      }
      #pragma unroll
      for (int nf = 0; nf < 4; ++nf) {
        int cr = wn * 64 + nf * 16 + l15;
        bf16x8 bh = Bsh[cr * 32 + (ch ^ swz(cr))];
        bf16x8 bl = Bsh[cr * 32 + ((ch + 1) ^ swz(cr))];
        #pragma unroll
        for (int mf = 0; mf < 2; ++mf) {
          f32x4 cc = acc[mf][nf];
          cc = __builtin_amdgcn_mfma_f32_16x16x32_bf16(ah[mf], bh, cc, 0, 0, 0);
          cc = __builtin_amdgcn_mfma_f32_16x16x32_bf16(al[mf], bh, cc, 0, 0, 0);
          cc = __builtin_amdgcn_mfma_f32_16x16x32_bf16(ah[mf], bl, cc, 0, 0, 0);
          acc[mf][nf] = cc;
        }
      }
    }

    #pragma unroll
    for (int nf = 0; nf < 4; ++nf) {
      int code = ct * 128 + wn * 64 + nf * 16 + l15;
      float sq = wsqs[code];
      #pragma unroll
      for (int mf = 0; mf < 2; ++mf)
        #pragma unroll
        for (int rg = 0; rg < 4; ++rg) {
          float s = fmaf(-2.f, acc[mf][nf][rg], sq);
          if (s < m1[mf][rg]) { m2[mf][rg] = m1[mf][rg]; m1[mf][rg] = s; i1[mf][rg] = code; }
          else if (s < m2[mf][rg]) m2[mf][rg] = s;
        }
    }
  }

  #pragma unroll
  for (int mk = 1; mk <= 8; mk <<= 1) {
    #pragma unroll
    for (int mf = 0; mf < 2; ++mf)
      #pragma unroll
      for (int rg = 0; rg < 4; ++rg) {
        float om1 = __shfl_xor(m1[mf][rg], mk);
        int   oi  = __shfl_xor(i1[mf][rg], mk);
        float om2 = __shfl_xor(m2[mf][rg], mk);
        bool bwin = (om1 < m1[mf][rg]) || (om1 == m1[mf][rg] && oi < i1[mf][rg]);
        float lose = bwin ? m1[mf][rg] : om1;
        m2[mf][rg] = fminf(fminf(m2[mf][rg], om2), lose);
        if (bwin) { m1[mf][rg] = om1; i1[mf][rg] = oi; }
      }
  }
  if (l15 == 0) {
    #pragma unroll
    for (int mf = 0; mf < 2; ++mf)
      #pragma unroll
      for (int rg = 0; rg < 4; ++rg) {
        int rl = wm * 32 + mf * 16 + kg * 4 + rg;
        Lm1[wn][rl] = m1[mf][rg];
        Lm2[wn][rl] = m2[mf][rg];
        Li1[wn][rl] = i1[mf][rg];
      }
  }
  __syncthreads();

  if (t < 128) {
    float a1 = Lm1[0][t], a2 = Lm2[0][t];
    int ai = Li1[0][t];
    float b1 = Lm1[1][t], b2 = Lm2[1][t];
    int bi = Li1[1][t];
    bool bwin = (b1 < a1) || (b1 == a1 && bi < ai);
    float lose = bwin ? a1 : b1;
    float gm1 = bwin ? b1 : a1;
    int gi = bwin ? bi : ai;
    float gm2 = fminf(fminf(a2, b2), lose);
    int row = row0 + t;
    if (gm2 - gm1 > TAU) {
      idxw[row] = gi;
      idxf[row] = (float)gi;
      atomicAdd(&count[gi], 1);
    } else {
      int p = atomicAdd(fb_count, 1);
      fb_list[p] = row;
    }
  }
}

// ---------------------------------------------------------------- exact fp32 fallback
__global__ __launch_bounds__(256) void k_fallback(
    const float* __restrict__ res, const float* __restrict__ W,
    const float* __restrict__ wsq, const int* __restrict__ fb_count,
    const int* __restrict__ fb_list,
    int* __restrict__ idxw, float* __restrict__ idxf,
    int* __restrict__ count, int stage)
{
  __shared__ float rr[128];
  __shared__ float sv[256];
  __shared__ int   si[256];
  int n = *fb_count;
  int t = threadIdx.x;
  for (int b = blockIdx.x; b < n; b += gridDim.x) {
    int row = fb_list[b];
    __syncthreads();
    if (t < 128) rr[t] = res[(size_t)row * DD + t];
    __syncthreads();
    float bm = 3.4e38f; int bi = 0;
    #pragma unroll
    for (int j = 0; j < 4; ++j) {
      int c = t + j * 256;
      const float4* wp = reinterpret_cast<const float4*>(W + ((size_t)stage * NC + c) * DD);
      float dot = 0.f;
      #pragma unroll 8
      for (int k = 0; k < 32; ++k) {
        float4 wv = wp[k];
        dot = fmaf(rr[4 * k + 0], wv.x, dot);
        dot = fmaf(rr[4 * k + 1], wv.y, dot);
        dot = fmaf(rr[4 * k + 2], wv.z, dot);
        dot = fmaf(rr[4 * k + 3], wv.w, dot);
      }
      float s = fmaf(-2.f, dot, wsq[stage * NC + c]);
      if (s < bm || (s == bm && c < bi)) { bm = s; bi = c; }
    }
    sv[t] = bm; si[t] = bi;
    __syncthreads();
    for (int sft = 128; sft > 0; sft >>= 1) {
      if (t < sft) {
        float ov = sv[t + sft]; int oi = si[t + sft];
        if (ov < sv[t] || (ov == sv[t] && oi < si[t])) { sv[t] = ov; si[t] = oi; }
      }
      __syncthreads();
    }
    if (t == 0) {
      int win = si[0];
      idxw[row] = win;
      idxf[row] = (float)win;
      atomicAdd(&count[win], 1);
    }
  }
}

// ---------------------------------------------------------------- prefix scan + pos reset
__global__ __launch_bounds__(1024) void k_scan(
    const int* __restrict__ count, int* __restrict__ offs, int* __restrict__ pos)
{
  __shared__ int sc[1024];
  int t = threadIdx.x;
  sc[t] = count[t];
  __syncthreads();
  for (int off = 1; off < 1024; off <<= 1) {
    int v = (t >= off) ? sc[t - off] : 0;
    __syncthreads();
    sc[t] += v;
    __syncthreads();
  }
  offs[t + 1] = sc[t];
  if (t == 0) offs[0] = 0;
  pos[t] = 0;
}

// ---------------------------------------------------------------- CSR scatter
__global__ __launch_bounds__(256) void k_scatter(
    const int* __restrict__ idxw, const int* __restrict__ offs,
    int* __restrict__ pos, int* __restrict__ rows_sorted)
{
  int r = blockIdx.x * 256 + threadIdx.x;
  int c = idxw[r];
  int slot = offs[c] + atomicAdd(&pos[c], 1);
  rows_sorted[slot] = r;
}

// ---------------------------------------------------------------- threefry2x32 (JAX-exact)
__device__ __forceinline__ unsigned rotl32(unsigned v, int r) { return (v << r) | (v >> (32 - r)); }

__device__ void threefry2x32(unsigned ks0, unsigned ks1, unsigned x0, unsigned x1,
                             unsigned& o0, unsigned& o1)
{
  unsigned ks2 = ks0 ^ ks1 ^ 0x1BD11BDAu;
  x0 += ks0; x1 += ks1;
  x0 += x1; x1 = rotl32(x1, 13); x1 ^= x0;
  x0 += x1; x1 = rotl32(x1, 15); x1 ^= x0;
  x0 += x1; x1 = rotl32(x1, 26); x1 ^= x0;
  x0 += x1; x1 = rotl32(x1, 6);  x1 ^= x0;
  x0 += ks1; x1 += ks2 + 1u;
  x0 += x1; x1 = rotl32(x1, 17); x1 ^= x0;
  x0 += x1; x1 = rotl32(x1, 29); x1 ^= x0;
  x0 += x1; x1 = rotl32(x1, 16); x1 ^= x0;
  x0 += x1; x1 = rotl32(x1, 24); x1 ^= x0;
  x0 += ks2; x1 += ks0 + 2u;
  x0 += x1; x1 = rotl32(x1, 13); x1 ^= x0;
  x0 += x1; x1 = rotl32(x1, 15); x1 ^= x0;
  x0 += x1; x1 = rotl32(x1, 26); x1 ^= x0;
  x0 += x1; x1 = rotl32(x1, 6);  x1 ^= x0;
  x0 += ks0; x1 += ks1 + 3u;
  x0 += x1; x1 = rotl32(x1, 17); x1 ^= x0;
  x0 += x1; x1 = rotl32(x1, 29); x1 ^= x0;
  x0 += x1; x1 = rotl32(x1, 16); x1 ^= x0;
  x0 += x1; x1 = rotl32(x1, 24); x1 ^= x0;
  x0 += ks1; x1 += ks2 + 4u;
  x0 += x1; x1 = rotl32(x1, 13); x1 ^= x0;
  x0 += x1; x1 = rotl32(x1, 15); x1 ^= x0;
  x0 += x1; x1 = rotl32(x1, 26); x1 ^= x0;
  x0 += x1; x1 = rotl32(x1, 6);  x1 ^= x0;
  x0 += ks2; x1 += ks0 + 5u;
  o0 = x0; o1 = x1;
}

// ---------------------------------------------------------------- EMA / dead codes (CSR gather, 8-way + unroll-4)
__global__ __launch_bounds__(1024) void k_finalize(
    const float* __restrict__ Ni_in, const float* __restrict__ mi_in,
    const int* __restrict__ count, const int* __restrict__ offs,
    const int* __restrict__ rows_sorted, const float* __restrict__ res_cur,
    float* __restrict__ outNi, float* __restrict__ outmi, float* __restrict__ outW,
    int stage)
{
  __shared__ float red[8][128];
  const float ONEMG = (float)(1.0 - 0.99);
  int c = blockIdx.x;
  int t = threadIdx.x;
  int d = t & 127;
  int jw = t >> 7;             // 0..7
  int cnt = count[c];
  int base = offs[c];
  const int* rs = rows_sorted + base;

  float sum = 0.f;
  int j = jw;
  for (; j + 24 < cnt; j += 32) {
    int r0 = rs[j];
    int r1 = rs[j + 8];
    int r2 = rs[j + 16];
    int r3 = rs[j + 24];
    float v0 = res_cur[(size_t)r0 * DD + d];
    float v1 = res_cur[(size_t)r1 * DD + d];
    float v2 = res_cur[(size_t)r2 * DD + d];
    float v3 = res_cur[(size_t)r3 * DD + d];
    sum += v0 + v1 + v2 + v3;
  }
  for (; j < cnt; j += 8)
    sum += res_cur[(size_t)rs[j] * DD + d];

  red[jw][d] = sum;
  __syncthreads();

  if (jw == 0) {
    float s = red[0][d] + red[1][d] + red[2][d] + red[3][d]
            + red[4][d] + red[5][d] + red[6][d] + red[7][d];
    float ni = Ni_in[stage * NC + c] * GAMMA_F + (float)cnt * ONEMG;
    float mm = mi_in[((size_t)stage * NC + c) * DD + d] * GAMMA_F + s * ONEMG;
    float w = mm / fmaxf(ni, 1e-8f);
    if (ni < 2.0f) {
      unsigned K0, K1, a0, a1, b0, b1, o0, o1;
      threefry2x32(0u, 42u, 0u, (unsigned)stage, K0, K1);
      threefry2x32(K0, K1, 0u, 2u, a0, a1);
      threefry2x32(K0, K1, 1u, 3u, b0, b1);
      unsigned bits;
      if (c < 512) { threefry2x32(a1, b1, (unsigned)c, (unsigned)(c + 512), o0, o1); bits = o0; }
      else         { threefry2x32(a1, b1, (unsigned)(c - 512), (unsigned)c, o0, o1); bits = o1; }
      int rid = (int)(bits & 32767u);
      w = res_cur[(size_t)rid * DD + d];
    }
    if (d == 0) outNi[stage * NC + c] = ni;
    size_t o = ((size_t)stage * NC + c) * DD + d;
    outmi[o] = mm;
    outW[o] = w;
  }
}

// ---------------------------------------------------------------- residual update (in-place) + bf16 split
__global__ __launch_bounds__(256) void k_update(
    float* __restrict__ res, const float* __restrict__ W,
    const int* __restrict__ idx, ushort* __restrict__ res_hl, int stage)
{
  int row = blockIdx.x * 8 + (threadIdx.x >> 5);
  int d4 = threadIdx.x & 31;
  int id = idx[row];
  float4 r = reinterpret_cast<const float4*>(res + (size_t)row * DD)[d4];
  float4 q = reinterpret_cast<const float4*>(W + ((size_t)stage * NC + id) * DD)[d4];
  float4 o;
  o.x = r.x - q.x; o.y = r.y - q.y; o.z = r.z - q.z; o.w = r.w - q.w;
  reinterpret_cast<float4*>(res + (size_t)row * DD)[d4] = o;
  ushort4 hi, lo;
  hi.x = f2bf(o.x); lo.x = f2bf(o.x - bf2f(hi.x));
  hi.y = f2bf(o.y); lo.y = f2bf(o.y - bf2f(hi.y));
  hi.z = f2bf(o.z); lo.z = f2bf(o.z - bf2f(hi.z));
  hi.w = f2bf(o.w); lo.w = f2bf(o.w - bf2f(hi.w));
  size_t g = ((size_t)row * 16 + (d4 >> 1)) * 2;
  *reinterpret_cast<ushort4*>(res_hl + g * 8 + (d4 & 1) * 4) = hi;
  *reinterpret_cast<ushort4*>(res_hl + (g + 1) * 8 + (d4 & 1) * 4) = lo;
}

// ---------------------------------------------------------------- logits + loss partials
__global__ __launch_bounds__(256) void k_final(
    const float* __restrict__ data, const float* __restrict__ res,
    float* __restrict__ logits, float* __restrict__ partials)
{
  __shared__ float tile[32][33];
  __shared__ float wsum[4];
  int b = blockIdx.z, s0 = blockIdx.x << 5, d0 = blockIdx.y << 5;
  int tx = threadIdx.x, ty = threadIdx.y;
  #pragma unroll
  for (int r = 0; r < 32; r += 8)
    tile[ty + r][tx] = res[((size_t)b * SS + s0 + ty + r) * DD + d0 + tx];
  __syncthreads();
  float l = 0.f;
  #pragma unroll
  for (int r = 0; r < 32; r += 8) {
    int dv = d0 + ty + r, s = s0 + tx;
    size_t o = ((size_t)b * DD + dv) * SS + s;
    float rv = tile[tx][ty + r];
    logits[o] = data[o] - rv;
    l = fmaf(rv, rv, l);
  }
  #pragma unroll
  for (int m = 1; m < 64; m <<= 1) l += __shfl_xor(l, m);
  int lin = ty * 32 + tx;
  if ((lin & 63) == 0) wsum[lin >> 6] = l;
  __syncthreads();
  if (lin == 0) {
    int bl = (blockIdx.z * gridDim.y + blockIdx.y) * gridDim.x + blockIdx.x;
    partials[bl] = wsum[0] + wsum[1] + wsum[2] + wsum[3];
  }
}

__global__ __launch_bounds__(1024) void k_loss_reduce(
    const float* __restrict__ partials, float* __restrict__ loss)
{
  __shared__ float ws[16];
  int t = threadIdx.x;
  float s = partials[t] + partials[t + 1024] + partials[t + 2048] + partials[t + 3072];
  #pragma unroll
  for (int m = 1; m < 64; m <<= 1) s += __shfl_xor(s, m);
  if ((t & 63) == 0) ws[t >> 6] = s;
  __syncthreads();
  if (t < 16) {
    float v = ws[t];
    #pragma unroll
    for (int m = 1; m < 16; m <<= 1) v += __shfl_xor(v, m);
    if (t == 0) loss[0] = v * (1.0f / 4194304.0f);
  }
}

// ---------------------------------------------------------------- launch
extern "C" void kernel_launch(void* const* d_in, const int* in_sizes, int n_in,
                              void* d_out, int out_size, void* d_ws, size_t ws_size,
                              hipStream_t stream)
{
  (void)in_sizes; (void)n_in; (void)out_size; (void)ws_size;
  const float* data = (const float*)d_in[0];
  const float* W    = (const float*)d_in[1];
  const float* Ni   = (const float*)d_in[2];
  const float* mi   = (const float*)d_in[3];

  float* out        = (float*)d_out;
  float* out_logits = out;
  float* out_loss   = out + (size_t)BB * DD * SS;
  float* out_idx    = out_loss + 1;
  float* out_Ni     = out_idx + (size_t)NQ * RR;
  float* out_mi     = out_Ni + (size_t)NQ * NC;
  float* out_W      = out_mi + (size_t)NQ * NC * DD;

  char* wp = (char*)d_ws;
  float*  resA        = (float*)wp;   wp += (size_t)RR * DD * 4;       // 16.78 MB
  ushort* res_hl      = (ushort*)wp;  wp += (size_t)RR * DD * 4;       // 16.78 MB
  ushort* w_hl        = (ushort*)wp;  wp += (size_t)NQ * NC * DD * 4;  // 4.19 MB
  float*  wsq         = (float*)wp;   wp += (size_t)NQ * NC * 4;
  int*    idxw        = (int*)wp;     wp += (size_t)RR * 4;
  int*    fb_list     = (int*)wp;     wp += (size_t)RR * 4;
  int*    rows_sorted = (int*)wp;     wp += (size_t)RR * 4;
  int*    count       = (int*)wp;     wp += (size_t)1025 * 4;          // count[1024] + fb_count
  int*    fb_count    = count + 1024;
  int*    pos         = (int*)wp;     wp += (size_t)NC * 4;
  int*    offs        = (int*)wp;     wp += (size_t)(NC + 1) * 4;
  float*  partials    = (float*)wp;   wp += (size_t)4096 * 4;

  k_transpose_in<<<dim3(SS / 32, DD / 32, BB), dim3(32, 8), 0, stream>>>(data, resA);
  k_split<<<RR * 16 / 256, 256, 0, stream>>>(resA, res_hl);
  k_wsq<<<(NQ * NC + 255) / 256, 256, 0, stream>>>(W, wsq);
  k_split<<<NQ * NC * 16 / 256, 256, 0, stream>>>(W, w_hl);

  for (int i = 0; i < NQ; ++i) {
    hipMemsetAsync(count, 0, 1025 * sizeof(int), stream);
    k_argmin<<<RR / 128, 512, 0, stream>>>(res_hl, w_hl, wsq, idxw,
                                           out_idx + (size_t)i * RR,
                                           count, fb_count, fb_list, i);
    k_fallback<<<512, 256, 0, stream>>>(resA, W, wsq, fb_count, fb_list,
                                        idxw, out_idx + (size_t)i * RR, count, i);
    k_scan<<<1, 1024, 0, stream>>>(count, offs, pos);
    k_scatter<<<RR / 256, 256, 0, stream>>>(idxw, offs, pos, rows_sorted);
    k_finalize<<<NC, 1024, 0, stream>>>(Ni, mi, count, offs, rows_sorted, resA,
                                        out_Ni, out_mi, out_W, i);
    k_update<<<RR / 8, 256, 0, stream>>>(resA, W, idxw, res_hl, i);
  }

  k_final<<<dim3(SS / 32, DD / 32, BB), dim3(32, 8), 0, stream>>>(data, resA, out_logits, partials);
  k_loss_reduce<<<1, 1024, 0, stream>>>(partials, out_loss);
}

// Round 8
// 783.630 us; speedup vs baseline: 3.0367x; 1.1537x over previous
//
#include <hip/hip_runtime.h>
#include <hip/hip_bf16.h>

#define NQ 8
#define NC 1024
#define DD 128
#define BB 16
#define SS 2048
#define RR (BB * SS)   // 32768 rows
#define GAMMA_F 0.99f
#define TAU 0.03f

typedef __attribute__((ext_vector_type(8))) short bf16x8;
typedef __attribute__((ext_vector_type(4))) float f32x4;

typedef __attribute__((address_space(3))) void lds_void;
typedef const __attribute__((address_space(1))) void g1_void;
__device__ __forceinline__ void gload16(const void* g, void* l) {
  __builtin_amdgcn_global_load_lds((g1_void*)g, (lds_void*)l, 16, 0, 0);
}

__device__ __forceinline__ ushort f2bf(float x) {
  __hip_bfloat16 b = __float2bfloat16(x);
  return *reinterpret_cast<ushort*>(&b);
}
__device__ __forceinline__ float bf2f(ushort u) {
  unsigned v = ((unsigned)u) << 16;
  return *reinterpret_cast<float*>(&v);
}

// 4-bit LDS granule swizzle: spreads 16 consecutive rows over all 8 bank-quads
__device__ __forceinline__ int swz(int r) {
  return ((r & 7) << 2) | ((r >> 3) & 1);
}

// ---------------------------------------------------------------- transpose in
__global__ __launch_bounds__(256) void k_transpose_in(
    const float* __restrict__ data, float* __restrict__ res)
{
  __shared__ float tile[32][33];
  int b = blockIdx.z;
  int s0 = blockIdx.x << 5, d0 = blockIdx.y << 5;
  int tx = threadIdx.x, ty = threadIdx.y;   // (32,8)
  #pragma unroll
  for (int r = 0; r < 32; r += 8)
    tile[ty + r][tx] = data[((size_t)b * DD + d0 + ty + r) * SS + s0 + tx];
  __syncthreads();
  #pragma unroll
  for (int r = 0; r < 32; r += 8)
    res[((size_t)b * SS + s0 + ty + r) * DD + d0 + tx] = tile[tx][ty + r];
}

// ---------------------------------------------------------------- ||W||^2
__global__ void k_wsq(const float* __restrict__ W, float* __restrict__ wsq)
{
  int c = blockIdx.x * blockDim.x + threadIdx.x;
  if (c >= NQ * NC) return;
  const float4* p = reinterpret_cast<const float4*>(W + (size_t)c * DD);
  float s = 0.f;
  #pragma unroll 8
  for (int k = 0; k < DD / 4; ++k) {
    float4 v = p[k];
    s += v.x * v.x + v.y * v.y + v.z * v.z + v.w * v.w;
  }
  wsq[c] = s;
}

// ---------------------------------------------------------------- bf16 hi/lo split
__global__ __launch_bounds__(256) void k_split(
    const float* __restrict__ src, ushort* __restrict__ dst)
{
  int fi = blockIdx.x * 256 + threadIdx.x;
  const float4* sp = reinterpret_cast<const float4*>(src) + (size_t)fi * 2;
  float4 a = sp[0], b = sp[1];
  ushort4 h0, h1, l0, l1;
  h0.x = f2bf(a.x); l0.x = f2bf(a.x - bf2f(h0.x));
  h0.y = f2bf(a.y); l0.y = f2bf(a.y - bf2f(h0.y));
  h0.z = f2bf(a.z); l0.z = f2bf(a.z - bf2f(h0.z));
  h0.w = f2bf(a.w); l0.w = f2bf(a.w - bf2f(h0.w));
  h1.x = f2bf(b.x); l1.x = f2bf(b.x - bf2f(h1.x));
  h1.y = f2bf(b.y); l1.y = f2bf(b.y - bf2f(h1.y));
  h1.z = f2bf(b.z); l1.z = f2bf(b.z - bf2f(h1.z));
  h1.w = f2bf(b.w); l1.w = f2bf(b.w - bf2f(h1.w));
  ushort4* dp = reinterpret_cast<ushort4*>(dst + (size_t)fi * 16);
  dp[0] = h0; dp[1] = h1; dp[2] = l0; dp[3] = l1;
}

// ---------------------------------------------------------------- MFMA argmin (pipelined)
// 512 thr = 8 waves: wm = w>>1 (4 row groups of 32), wn = w&1 (2 col halves of 64).
// A frags held in registers (16 bf16x8); B double-buffered in LDS with counted vmcnt.
__global__ __launch_bounds__(512, 2) void k_argmin(
    const ushort* __restrict__ res_hl, const ushort* __restrict__ w_hl,
    const float* __restrict__ wsq,
    int* __restrict__ idxw, float* __restrict__ idxf,
    int* __restrict__ count, int* __restrict__ fb_count,
    int* __restrict__ fb_list, int stage)
{
  __shared__ bf16x8 S[8192];     // 128 KiB: buf0 = S, buf1 = S + 4096
  __shared__ float Lm1[2][128], Lm2[2][128];
  __shared__ int   Li1[2][128];

  const int t = threadIdx.x;
  const int l = t & 63;
  const int w = t >> 6;
  const int wm = w >> 1;         // 0..3 (row group of 32)
  const int wn = w & 1;          // 0..1 (col half of 64)
  const int row0 = blockIdx.x * 128;
  const int l15 = l & 15, kg = l >> 4;
  const float* wsqs = wsq + stage * NC;

  // ---- stage A into buf0, B(0) into buf1 (16 loads in flight)
  #pragma unroll
  for (int it = 0; it < 8; ++it) {
    int fi = it * 512 + t;
    int r = fi >> 5, sc = fi & 31;
    gload16(res_hl + ((size_t)(row0 + r) * 32 + (sc ^ swz(r))) * 8, &S[fi]);
  }
  #pragma unroll
  for (int it = 0; it < 8; ++it) {
    int fi = it * 512 + t;
    int cr = fi >> 5, sc = fi & 31;
    gload16(w_hl + ((size_t)(stage * NC + cr) * 32 + (sc ^ swz(cr))) * 8, &S[4096 + fi]);
  }
  asm volatile("s_waitcnt vmcnt(8)" ::: "memory");   // A landed; B(0) still in flight
  __builtin_amdgcn_sched_barrier(0);
  __builtin_amdgcn_s_barrier();

  // ---- A fragments -> registers (once)
  bf16x8 ah[2][4], al[2][4];
  #pragma unroll
  for (int mf = 0; mf < 2; ++mf)
    #pragma unroll
    for (int ks = 0; ks < 4; ++ks) {
      int r = wm * 32 + mf * 16 + l15;
      int ch = ks * 8 + kg * 2;
      ah[mf][ks] = S[r * 32 + (ch ^ swz(r))];
      al[mf][ks] = S[r * 32 + ((ch + 1) ^ swz(r))];
    }
  asm volatile("s_waitcnt lgkmcnt(0)" ::: "memory");
  __builtin_amdgcn_sched_barrier(0);
  __builtin_amdgcn_s_barrier();                      // buf0 free now

  // ---- issue B(1) into buf0
  #pragma unroll
  for (int it = 0; it < 8; ++it) {
    int fi = it * 512 + t;
    int cr = fi >> 5, sc = fi & 31;
    gload16(w_hl + ((size_t)(stage * NC + 128 + cr) * 32 + (sc ^ swz(cr))) * 8, &S[fi]);
  }

  float m1[2][4], m2[2][4];
  int i1[2][4];
  #pragma unroll
  for (int mf = 0; mf < 2; ++mf)
    #pragma unroll
    for (int rg = 0; rg < 4; ++rg) { m1[mf][rg] = 3.4e38f; m2[mf][rg] = 3.4e38f; i1[mf][rg] = 0; }

  for (int ct = 0; ct < 8; ++ct) {
    // B(ct) resident once outstanding <= 8 (the newer tile's loads)
    if (ct < 7) asm volatile("s_waitcnt vmcnt(8)" ::: "memory");
    else        asm volatile("s_waitcnt vmcnt(0)" ::: "memory");
    __builtin_amdgcn_sched_barrier(0);
    __builtin_amdgcn_s_barrier();

    const bf16x8* Bb = &S[((ct + 1) & 1) ? 4096 : 0];

    f32x4 zero = {0.f, 0.f, 0.f, 0.f};
    f32x4 acc[2][4];
    #pragma unroll
    for (int mf = 0; mf < 2; ++mf)
      #pragma unroll
      for (int nf = 0; nf < 4; ++nf) acc[mf][nf] = zero;

    #pragma unroll
    for (int ks = 0; ks < 4; ++ks) {
      const int ch = ks * 8 + kg * 2;
      #pragma unroll
      for (int nf = 0; nf < 4; ++nf) {
        int cr = wn * 64 + nf * 16 + l15;
        bf16x8 bh = Bb[cr * 32 + (ch ^ swz(cr))];
        bf16x8 bl = Bb[cr * 32 + ((ch + 1) ^ swz(cr))];
        #pragma unroll
        for (int mf = 0; mf < 2; ++mf) {
          f32x4 cc = acc[mf][nf];
          cc = __builtin_amdgcn_mfma_f32_16x16x32_bf16(ah[mf][ks], bh, cc, 0, 0, 0);
          cc = __builtin_amdgcn_mfma_f32_16x16x32_bf16(al[mf][ks], bh, cc, 0, 0, 0);
          cc = __builtin_amdgcn_mfma_f32_16x16x32_bf16(ah[mf][ks], bl, cc, 0, 0, 0);
          acc[mf][nf] = cc;
        }
      }
    }

    // fold scores into running (m1, i1, m2)
    #pragma unroll
    for (int nf = 0; nf < 4; ++nf) {
      int code = ct * 128 + wn * 64 + nf * 16 + l15;
      float sq = wsqs[code];
      #pragma unroll
      for (int mf = 0; mf < 2; ++mf)
        #pragma unroll
        for (int rg = 0; rg < 4; ++rg) {
          float s = fmaf(-2.f, acc[mf][nf][rg], sq);
          if (s < m1[mf][rg]) { m2[mf][rg] = m1[mf][rg]; m1[mf][rg] = s; i1[mf][rg] = code; }
          else if (s < m2[mf][rg]) m2[mf][rg] = s;
        }
    }

    __builtin_amdgcn_sched_barrier(0);
    __builtin_amdgcn_s_barrier();     // all waves done reading Bb
    if (ct + 2 < 8) {                 // refill the buffer just consumed
      bf16x8* dst = &S[((ct + 1) & 1) ? 4096 : 0];
      #pragma unroll
      for (int it = 0; it < 8; ++it) {
        int fi = it * 512 + t;
        int cr = fi >> 5, sc = fi & 31;
        gload16(w_hl + ((size_t)(stage * NC + (ct + 2) * 128 + cr) * 32 + (sc ^ swz(cr))) * 8,
                &dst[fi]);
      }
    }
  }

  // butterfly over the 16 col-classes per row
  #pragma unroll
  for (int mk = 1; mk <= 8; mk <<= 1) {
    #pragma unroll
    for (int mf = 0; mf < 2; ++mf)
      #pragma unroll
      for (int rg = 0; rg < 4; ++rg) {
        float om1 = __shfl_xor(m1[mf][rg], mk);
        int   oi  = __shfl_xor(i1[mf][rg], mk);
        float om2 = __shfl_xor(m2[mf][rg], mk);
        bool bwin = (om1 < m1[mf][rg]) || (om1 == m1[mf][rg] && oi < i1[mf][rg]);
        float lose = bwin ? m1[mf][rg] : om1;
        m2[mf][rg] = fminf(fminf(m2[mf][rg], om2), lose);
        if (bwin) { m1[mf][rg] = om1; i1[mf][rg] = oi; }
      }
  }
  if (l15 == 0) {
    #pragma unroll
    for (int mf = 0; mf < 2; ++mf)
      #pragma unroll
      for (int rg = 0; rg < 4; ++rg) {
        int rl = wm * 32 + mf * 16 + kg * 4 + rg;
        Lm1[wn][rl] = m1[mf][rg];
        Lm2[wn][rl] = m2[mf][rg];
        Li1[wn][rl] = i1[mf][rg];
      }
  }
  __syncthreads();

  if (t < 128) {
    float a1 = Lm1[0][t], a2 = Lm2[0][t];
    int ai = Li1[0][t];
    float b1 = Lm1[1][t], b2 = Lm2[1][t];
    int bi = Li1[1][t];
    bool bwin = (b1 < a1) || (b1 == a1 && bi < ai);
    float lose = bwin ? a1 : b1;
    float gm1 = bwin ? b1 : a1;
    int gi = bwin ? bi : ai;
    float gm2 = fminf(fminf(a2, b2), lose);
    int row = row0 + t;
    if (gm2 - gm1 > TAU) {
      idxw[row] = gi;
      idxf[row] = (float)gi;
      atomicAdd(&count[gi], 1);
    } else {
      int p = atomicAdd(fb_count, 1);
      fb_list[p] = row;
    }
  }
}

// ---------------------------------------------------------------- exact fp32 fallback
__global__ __launch_bounds__(256) void k_fallback(
    const float* __restrict__ res, const float* __restrict__ W,
    const float* __restrict__ wsq, const int* __restrict__ fb_count,
    const int* __restrict__ fb_list,
    int* __restrict__ idxw, float* __restrict__ idxf,
    int* __restrict__ count, int stage)
{
  __shared__ float rr[128];
  __shared__ float sv[256];
  __shared__ int   si[256];
  int n = *fb_count;
  int t = threadIdx.x;
  for (int b = blockIdx.x; b < n; b += gridDim.x) {
    int row = fb_list[b];
    __syncthreads();
    if (t < 128) rr[t] = res[(size_t)row * DD + t];
    __syncthreads();
    float bm = 3.4e38f; int bi = 0;
    #pragma unroll
    for (int j = 0; j < 4; ++j) {
      int c = t + j * 256;
      const float4* wp = reinterpret_cast<const float4*>(W + ((size_t)stage * NC + c) * DD);
      float dot = 0.f;
      #pragma unroll 8
      for (int k = 0; k < 32; ++k) {
        float4 wv = wp[k];
        dot = fmaf(rr[4 * k + 0], wv.x, dot);
        dot = fmaf(rr[4 * k + 1], wv.y, dot);
        dot = fmaf(rr[4 * k + 2], wv.z, dot);
        dot = fmaf(rr[4 * k + 3], wv.w, dot);
      }
      float s = fmaf(-2.f, dot, wsq[stage * NC + c]);
      if (s < bm || (s == bm && c < bi)) { bm = s; bi = c; }
    }
    sv[t] = bm; si[t] = bi;
    __syncthreads();
    for (int sft = 128; sft > 0; sft >>= 1) {
      if (t < sft) {
        float ov = sv[t + sft]; int oi = si[t + sft];
        if (ov < sv[t] || (ov == sv[t] && oi < si[t])) { sv[t] = ov; si[t] = oi; }
      }
      __syncthreads();
    }
    if (t == 0) {
      int win = si[0];
      idxw[row] = win;
      idxf[row] = (float)win;
      atomicAdd(&count[win], 1);
    }
  }
}

// ---------------------------------------------------------------- prefix scan + reset for next stage
__global__ __launch_bounds__(1024) void k_scan(
    int* __restrict__ count, int* __restrict__ offs, int* __restrict__ pos)
{
  __shared__ int sc[1024];
  int t = threadIdx.x;
  sc[t] = count[t];
  __syncthreads();
  for (int off = 1; off < 1024; off <<= 1) {
    int v = (t >= off) ? sc[t - off] : 0;
    __syncthreads();
    sc[t] += v;
    __syncthreads();
  }
  offs[t + 1] = sc[t];
  if (t == 0) { offs[0] = 0; count[1024] = 0; }   // count[1024] == fb_count
  pos[t] = 0;
  count[t] = 0;   // ready for next stage's argmin
}

// ---------------------------------------------------------------- CSR scatter
__global__ __launch_bounds__(256) void k_scatter(
    const int* __restrict__ idxw, const int* __restrict__ offs,
    int* __restrict__ pos, int* __restrict__ rows_sorted)
{
  int r = blockIdx.x * 256 + threadIdx.x;
  int c = idxw[r];
  int slot = offs[c] + atomicAdd(&pos[c], 1);
  rows_sorted[slot] = r;
}

// ---------------------------------------------------------------- threefry2x32 (JAX-exact)
__device__ __forceinline__ unsigned rotl32(unsigned v, int r) { return (v << r) | (v >> (32 - r)); }

__device__ void threefry2x32(unsigned ks0, unsigned ks1, unsigned x0, unsigned x1,
                             unsigned& o0, unsigned& o1)
{
  unsigned ks2 = ks0 ^ ks1 ^ 0x1BD11BDAu;
  x0 += ks0; x1 += ks1;
  x0 += x1; x1 = rotl32(x1, 13); x1 ^= x0;
  x0 += x1; x1 = rotl32(x1, 15); x1 ^= x0;
  x0 += x1; x1 = rotl32(x1, 26); x1 ^= x0;
  x0 += x1; x1 = rotl32(x1, 6);  x1 ^= x0;
  x0 += ks1; x1 += ks2 + 1u;
  x0 += x1; x1 = rotl32(x1, 17); x1 ^= x0;
  x0 += x1; x1 = rotl32(x1, 29); x1 ^= x0;
  x0 += x1; x1 = rotl32(x1, 16); x1 ^= x0;
  x0 += x1; x1 = rotl32(x1, 24); x1 ^= x0;
  x0 += ks2; x1 += ks0 + 2u;
  x0 += x1; x1 = rotl32(x1, 13); x1 ^= x0;
  x0 += x1; x1 = rotl32(x1, 15); x1 ^= x0;
  x0 += x1; x1 = rotl32(x1, 26); x1 ^= x0;
  x0 += x1; x1 = rotl32(x1, 6);  x1 ^= x0;
  x0 += ks0; x1 += ks1 + 3u;
  x0 += x1; x1 = rotl32(x1, 17); x1 ^= x0;
  x0 += x1; x1 = rotl32(x1, 29); x1 ^= x0;
  x0 += x1; x1 = rotl32(x1, 16); x1 ^= x0;
  x0 += x1; x1 = rotl32(x1, 24); x1 ^= x0;
  x0 += ks1; x1 += ks2 + 4u;
  x0 += x1; x1 = rotl32(x1, 13); x1 ^= x0;
  x0 += x1; x1 = rotl32(x1, 15); x1 ^= x0;
  x0 += x1; x1 = rotl32(x1, 26); x1 ^= x0;
  x0 += x1; x1 = rotl32(x1, 6);  x1 ^= x0;
  x0 += ks2; x1 += ks0 + 5u;
  o0 = x0; o1 = x1;
}

// ---------------------------------------------------------------- EMA / dead codes (CSR gather, 8-way + unroll-4)
__global__ __launch_bounds__(1024) void k_finalize(
    const float* __restrict__ Ni_in, const float* __restrict__ mi_in,
    const int* __restrict__ count, const int* __restrict__ offs,
    const int* __restrict__ rows_sorted, const float* __restrict__ res_cur,
    float* __restrict__ outNi, float* __restrict__ outmi, float* __restrict__ outW,
    int stage)
{
  __shared__ float red[8][128];
  const float ONEMG = (float)(1.0 - 0.99);
  int c = blockIdx.x;
  int t = threadIdx.x;
  int d = t & 127;
  int jw = t >> 7;             // 0..7
  int cnt = count[c];
  int base = offs[c];
  const int* rs = rows_sorted + base;

  float sum = 0.f;
  int j = jw;
  for (; j + 24 < cnt; j += 32) {
    int r0 = rs[j];
    int r1 = rs[j + 8];
    int r2 = rs[j + 16];
    int r3 = rs[j + 24];
    float v0 = res_cur[(size_t)r0 * DD + d];
    float v1 = res_cur[(size_t)r1 * DD + d];
    float v2 = res_cur[(size_t)r2 * DD + d];
    float v3 = res_cur[(size_t)r3 * DD + d];
    sum += v0 + v1 + v2 + v3;
  }
  for (; j < cnt; j += 8)
    sum += res_cur[(size_t)rs[j] * DD + d];

  red[jw][d] = sum;
  __syncthreads();

  if (jw == 0) {
    float s = red[0][d] + red[1][d] + red[2][d] + red[3][d]
            + red[4][d] + red[5][d] + red[6][d] + red[7][d];
    float ni = Ni_in[stage * NC + c] * GAMMA_F + (float)cnt * ONEMG;
    float mm = mi_in[((size_t)stage * NC + c) * DD + d] * GAMMA_F + s * ONEMG;
    float w = mm / fmaxf(ni, 1e-8f);
    if (ni < 2.0f) {
      unsigned K0, K1, a0, a1, b0, b1, o0, o1;
      threefry2x32(0u, 42u, 0u, (unsigned)stage, K0, K1);
      threefry2x32(K0, K1, 0u, 2u, a0, a1);
      threefry2x32(K0, K1, 1u, 3u, b0, b1);
      unsigned bits;
      if (c < 512) { threefry2x32(a1, b1, (unsigned)c, (unsigned)(c + 512), o0, o1); bits = o0; }
      else         { threefry2x32(a1, b1, (unsigned)(c - 512), (unsigned)c, o0, o1); bits = o1; }
      int rid = (int)(bits & 32767u);
      w = res_cur[(size_t)rid * DD + d];
    }
    if (d == 0) outNi[stage * NC + c] = ni;
    size_t o = ((size_t)stage * NC + c) * DD + d;
    outmi[o] = mm;
    outW[o] = w;
  }
}

// ---------------------------------------------------------------- residual update (in-place) + bf16 split
__global__ __launch_bounds__(256) void k_update(
    float* __restrict__ res, const float* __restrict__ W,
    const int* __restrict__ idx, ushort* __restrict__ res_hl, int stage)
{
  int row = blockIdx.x * 8 + (threadIdx.x >> 5);
  int d4 = threadIdx.x & 31;
  int id = idx[row];
  float4 r = reinterpret_cast<const float4*>(res + (size_t)row * DD)[d4];
  float4 q = reinterpret_cast<const float4*>(W + ((size_t)stage * NC + id) * DD)[d4];
  float4 o;
  o.x = r.x - q.x; o.y = r.y - q.y; o.z = r.z - q.z; o.w = r.w - q.w;
  reinterpret_cast<float4*>(res + (size_t)row * DD)[d4] = o;
  ushort4 hi, lo;
  hi.x = f2bf(o.x); lo.x = f2bf(o.x - bf2f(hi.x));
  hi.y = f2bf(o.y); lo.y = f2bf(o.y - bf2f(hi.y));
  hi.z = f2bf(o.z); lo.z = f2bf(o.z - bf2f(hi.z));
  hi.w = f2bf(o.w); lo.w = f2bf(o.w - bf2f(hi.w));
  size_t g = ((size_t)row * 16 + (d4 >> 1)) * 2;
  *reinterpret_cast<ushort4*>(res_hl + g * 8 + (d4 & 1) * 4) = hi;
  *reinterpret_cast<ushort4*>(res_hl + (g + 1) * 8 + (d4 & 1) * 4) = lo;
}

// ---------------------------------------------------------------- logits + loss partials
__global__ __launch_bounds__(256) void k_final(
    const float* __restrict__ data, const float* __restrict__ res,
    float* __restrict__ logits, float* __restrict__ partials)
{
  __shared__ float tile[32][33];
  __shared__ float wsum[4];
  int b = blockIdx.z, s0 = blockIdx.x << 5, d0 = blockIdx.y << 5;
  int tx = threadIdx.x, ty = threadIdx.y;
  #pragma unroll
  for (int r = 0; r < 32; r += 8)
    tile[ty + r][tx] = res[((size_t)b * SS + s0 + ty + r) * DD + d0 + tx];
  __syncthreads();
  float l = 0.f;
  #pragma unroll
  for (int r = 0; r < 32; r += 8) {
    int dv = d0 + ty + r, s = s0 + tx;
    size_t o = ((size_t)b * DD + dv) * SS + s;
    float rv = tile[tx][ty + r];
    logits[o] = data[o] - rv;
    l = fmaf(rv, rv, l);
  }
  #pragma unroll
  for (int m = 1; m < 64; m <<= 1) l += __shfl_xor(l, m);
  int lin = ty * 32 + tx;
  if ((lin & 63) == 0) wsum[lin >> 6] = l;
  __syncthreads();
  if (lin == 0) {
    int bl = (blockIdx.z * gridDim.y + blockIdx.y) * gridDim.x + blockIdx.x;
    partials[bl] = wsum[0] + wsum[1] + wsum[2] + wsum[3];
  }
}

__global__ __launch_bounds__(1024) void k_loss_reduce(
    const float* __restrict__ partials, float* __restrict__ loss)
{
  __shared__ float ws[16];
  int t = threadIdx.x;
  float s = partials[t] + partials[t + 1024] + partials[t + 2048] + partials[t + 3072];
  #pragma unroll
  for (int m = 1; m < 64; m <<= 1) s += __shfl_xor(s, m);
  if ((t & 63) == 0) ws[t >> 6] = s;
  __syncthreads();
  if (t < 16) {
    float v = ws[t];
    #pragma unroll
    for (int m = 1; m < 16; m <<= 1) v += __shfl_xor(v, m);
    if (t == 0) loss[0] = v * (1.0f / 4194304.0f);
  }
}

// ---------------------------------------------------------------- launch
extern "C" void kernel_launch(void* const* d_in, const int* in_sizes, int n_in,
                              void* d_out, int out_size, void* d_ws, size_t ws_size,
                              hipStream_t stream)
{
  (void)in_sizes; (void)n_in; (void)out_size; (void)ws_size;
  const float* data = (const float*)d_in[0];
  const float* W    = (const float*)d_in[1];
  const float* Ni   = (const float*)d_in[2];
  const float* mi   = (const float*)d_in[3];

  float* out        = (float*)d_out;
  float* out_logits = out;
  float* out_loss   = out + (size_t)BB * DD * SS;
  float* out_idx    = out_loss + 1;
  float* out_Ni     = out_idx + (size_t)NQ * RR;
  float* out_mi     = out_Ni + (size_t)NQ * NC;
  float* out_W      = out_mi + (size_t)NQ * NC * DD;

  char* wp = (char*)d_ws;
  float*  resA        = (float*)wp;   wp += (size_t)RR * DD * 4;       // 16.78 MB
  ushort* res_hl      = (ushort*)wp;  wp += (size_t)RR * DD * 4;       // 16.78 MB
  ushort* w_hl        = (ushort*)wp;  wp += (size_t)NQ * NC * DD * 4;  // 4.19 MB
  float*  wsq         = (float*)wp;   wp += (size_t)NQ * NC * 4;
  int*    idxw        = (int*)wp;     wp += (size_t)RR * 4;
  int*    fb_list     = (int*)wp;     wp += (size_t)RR * 4;
  int*    rows_sorted = (int*)wp;     wp += (size_t)RR * 4;
  int*    count       = (int*)wp;     wp += (size_t)1025 * 4;          // count[1024] + fb_count
  int*    fb_count    = count + 1024;
  int*    pos         = (int*)wp;     wp += (size_t)NC * 4;
  int*    offs        = (int*)wp;     wp += (size_t)(NC + 1) * 4;
  float*  partials    = (float*)wp;   wp += (size_t)4096 * 4;

  k_transpose_in<<<dim3(SS / 32, DD / 32, BB), dim3(32, 8), 0, stream>>>(data, resA);
  k_split<<<RR * 16 / 256, 256, 0, stream>>>(resA, res_hl);
  k_wsq<<<(NQ * NC + 255) / 256, 256, 0, stream>>>(W, wsq);
  k_split<<<NQ * NC * 16 / 256, 256, 0, stream>>>(W, w_hl);
  hipMemsetAsync(count, 0, 1025 * sizeof(int), stream);   // first stage only; k_scan resets after

  for (int i = 0; i < NQ; ++i) {
    k_argmin<<<RR / 128, 512, 0, stream>>>(res_hl, w_hl, wsq, idxw,
                                           out_idx + (size_t)i * RR,
                                           count, fb_count, fb_list, i);
    k_fallback<<<512, 256, 0, stream>>>(resA, W, wsq, fb_count, fb_list,
                                        idxw, out_idx + (size_t)i * RR, count, i);
    k_scan<<<1, 1024, 0, stream>>>(count, offs, pos);
    k_scatter<<<RR / 256, 256, 0, stream>>>(idxw, offs, pos, rows_sorted);
    k_finalize<<<NC, 1024, 0, stream>>>(Ni, mi, count, offs, rows_sorted, resA,
                                        out_Ni, out_mi, out_W, i);
    k_update<<<RR / 8, 256, 0, stream>>>(resA, W, idxw, res_hl, i);
  }

  k_final<<<dim3(SS / 32, DD / 32, BB), dim3(32, 8), 0, stream>>>(data, resA, out_logits, partials);
  k_loss_reduce<<<1, 1024, 0, stream>>>(partials, out_loss);
}